// Round 3
// baseline (97.187 us; speedup 1.0000x reference)
//
#include <hip/hip_runtime.h>
#include <math.h>

// ---- problem constants ----
#define SEQ 64
#define NSAMP 16384
#define NHARM 32
#define NWS 512
#define NSTEP 256
#define BE 128            // B*E = 8*16
#define NFRAMES 8192      // BE * SEQ

typedef _Float16 half8 __attribute__((ext_vector_type(8)));
typedef _Float16 half4v __attribute__((ext_vector_type(4)));
typedef float f32x4 __attribute__((ext_vector_type(4)));

__device__ __forceinline__ float sin_rev(float x) {  // sin(2*pi*x)
  float r; asm("v_sin_f32 %0, %1" : "=v"(r) : "v"(x)); return r;
}
__device__ __forceinline__ float cos_rev(float x) {  // cos(2*pi*x)
  float r; asm("v_cos_f32 %0, %1" : "=v"(r) : "v"(x)); return r;
}
__device__ __forceinline__ float clip01(float v) { return fminf(fmaxf(v, 0.0f), 1.0f); }

__device__ __forceinline__ float f0_to_norm(float f0v, float bl) {
  const float NYQ = 11025.0f;
  const float MIN_F0 = 20.0f / 11025.0f;
  const float F0_DIFF = 780.0f / 11025.0f;
  float v = fminf(fmaxf(f0v, -0.5f), 0.5f);
  float erb = (0.108f * (bl * NYQ) + 24.7f) / NYQ;
  float fv = clip01(bl + v * erb);
  return MIN_F0 + fv * F0_DIFF;
}

// ---------------------------------------------------------------------------
// Kernel 1: per-(b,e) phase scan (unchanged from R2).
// ---------------------------------------------------------------------------
__global__ __launch_bounds__(256) void phase_k(const float* __restrict__ f0,
                                               const float* __restrict__ f0b,
                                               float* __restrict__ qphase) {
  const int be = blockIdx.x;
  const int tid = threadIdx.x;
  __shared__ float f0n_s[SEQ];
  __shared__ double tsum[256];
  __shared__ float qbuf[4096];
  const float bl = f0b[be];
  if (tid < SEQ) f0n_s[tid] = f0_to_norm(f0[be * SEQ + tid], bl);
  __syncthreads();

  double carry = 0.0;
  for (int ch = 0; ch < 4; ++ch) {
    const int base = ch * 4096 + tid * 16;
    float fv[16];
    double loc = 0.0;
#pragma unroll
    for (int i = 0; i < 16; ++i) {
      int t = base + i;
      float pos = ((float)t + 0.5f) * (1.0f / 256.0f) - 0.5f;
      pos = fminf(fmaxf(pos, 0.0f), 63.0f);
      int i0 = (int)pos;
      int i1 = min(i0 + 1, 63);
      float w = pos - (float)i0;
      float fund = f0n_s[i0] * (1.0f - w) + f0n_s[i1] * w;
      fv[i] = fund;
      loc += (double)fund;
    }
    tsum[tid] = loc;
    __syncthreads();
    for (int off = 1; off < 256; off <<= 1) {
      double add = (tid >= off) ? tsum[tid - off] : 0.0;
      __syncthreads();
      tsum[tid] += add;
      __syncthreads();
    }
    double prefix = carry + ((tid > 0) ? tsum[tid - 1] : 0.0);
    double total = tsum[255];
    double run = prefix;
#pragma unroll
    for (int i = 0; i < 16; ++i) {
      run += (double)fv[i];
      double r = run - 2.0 * floor(run * 0.5);   // mod 2 -> [0,2)
      qbuf[tid * 16 + i] = (float)r;
    }
    carry += total;
    __syncthreads();
    for (int i = 0; i < 16; ++i)
      qphase[(size_t)be * NSAMP + ch * 4096 + i * 256 + tid] = qbuf[i * 256 + tid];
    __syncthreads();
  }
}

// ---------------------------------------------------------------------------
// Kernel 2: twiddle tables. W1[256][512]: rows 0..127 cos(2pi*m*n/512),
// rows 128..255 sin. W2[512][256]: cols 0..127 cos(2pi*k*n/512), 128..255 sin.
// ---------------------------------------------------------------------------
__global__ __launch_bounds__(256) void wgen_k(_Float16* __restrict__ W1,
                                              _Float16* __restrict__ W2) {
  const int bid = blockIdx.x;
  const int tid = threadIdx.x;
  if (bid < 256) {
    const int m = bid, k = m & 127;
    const bool isSin = m >= 128;
    for (int n = tid; n < 512; n += 256) {
      int a = (k * n) & 511;
      float ph = (float)a * (1.0f / 512.0f);
      W1[m * 512 + n] = (_Float16)(isSin ? sin_rev(ph) : cos_rev(ph));
    }
  } else {
    const int n = bid - 256;
    const int kap = tid;          // 0..255
    const int k = kap & 127;
    const bool isSin = kap >= 128;
    int a = (k * n) & 511;
    float ph = (float)a * (1.0f / 512.0f);
    W2[n * 256 + kap] = (_Float16)(isSin ? sin_rev(ph) : cos_rev(ph));
  }
}

// ---------------------------------------------------------------------------
// Kernel 3: Hann window + f16 convert. XW[f][n] = frames[f][n]*hann[n]. No
// transpose needed: frames are the GEMM N-side with K(samples) contiguous.
// ---------------------------------------------------------------------------
__global__ __launch_bounds__(256) void win_k(const float* __restrict__ x,
                                             _Float16* __restrict__ xw) {
  const int idx = blockIdx.x * 256 + threadIdx.x;  // float4 index, grid 4096
  float4 v = ((const float4*)x)[idx];
  const int n = (idx * 4) & 511;
  half4v o;
  float w0 = 0.5f - 0.5f * cos_rev((float)(n + 0) * (1.0f / 512.0f));
  float w1 = 0.5f - 0.5f * cos_rev((float)(n + 1) * (1.0f / 512.0f));
  float w2 = 0.5f - 0.5f * cos_rev((float)(n + 2) * (1.0f / 512.0f));
  float w3 = 0.5f - 0.5f * cos_rev((float)(n + 3) * (1.0f / 512.0f));
  o[0] = (_Float16)(v.x * w0);
  o[1] = (_Float16)(v.y * w1);
  o[2] = (_Float16)(v.z * w2);
  o[3] = (_Float16)(v.w * w3);
  ((half4v*)xw)[idx] = o;
}

// ---------------------------------------------------------------------------
// Kernel 4: GEMM template. C[M][N] f32 = A[M][K] * B[N][K]^T, A/B f16 stored
// row-major with K contiguous. grid = (N/128, M/64); 128 threads = 2 waves,
// each wave a 64x64 tile (4x4 of 16x16x32 MFMA frags). BK=128 single-buffered.
// LDS granule-XOR swizzle (kg ^= row&7) for conflict-free ds_read_b128.
// ---------------------------------------------------------------------------
__global__ __launch_bounds__(128) void gemm_k(const _Float16* __restrict__ A,
                                              const _Float16* __restrict__ B,
                                              float* __restrict__ C,
                                              int Kt, int Nt) {
  const int bn0 = blockIdx.x * 128;
  const int m0 = blockIdx.y * 64;
  const int tid = threadIdx.x;
  const int wave = tid >> 6, lane = tid & 63;
  const int r = lane & 15, q = lane >> 4;
  __shared__ __align__(16) _Float16 Asw[64 * 128];    // 16 KB
  __shared__ __align__(16) _Float16 Bsw[128 * 128];   // 32 KB

  f32x4 acc[4][4] = {};
  const int n0 = bn0 + wave * 64;

  for (int kk = 0; kk < Kt; kk += 128) {
    // stage A tile: 64 rows x 16 granules(16B)
#pragma unroll
    for (int it = 0; it < 8; ++it) {
      int g = it * 128 + tid;
      int row = g >> 4, kg = g & 15;
      half8 v = *(const half8*)(A + (size_t)(m0 + row) * Kt + kk + kg * 8);
      *(half8*)(Asw + row * 128 + (kg ^ (row & 7)) * 8) = v;
    }
    // stage B tile: 128 rows x 16 granules
#pragma unroll
    for (int it = 0; it < 16; ++it) {
      int g = it * 128 + tid;
      int row = g >> 4, kg = g & 15;
      half8 v = *(const half8*)(B + (size_t)(bn0 + row) * Kt + kk + kg * 8);
      *(half8*)(Bsw + row * 128 + (kg ^ (row & 7)) * 8) = v;
    }
    __syncthreads();
#pragma unroll
    for (int ks = 0; ks < 4; ++ks) {
      half8 af[4], bf[4];
#pragma unroll
      for (int mi = 0; mi < 4; ++mi) {
        int row = mi * 16 + r;
        int kg = ks * 4 + q;
        af[mi] = *(const half8*)(Asw + row * 128 + (kg ^ (row & 7)) * 8);
      }
#pragma unroll
      for (int ni = 0; ni < 4; ++ni) {
        int row = wave * 64 + ni * 16 + r;
        int kg = ks * 4 + q;
        bf[ni] = *(const half8*)(Bsw + row * 128 + (kg ^ (row & 7)) * 8);
      }
#pragma unroll
      for (int mi = 0; mi < 4; ++mi)
#pragma unroll
        for (int ni = 0; ni < 4; ++ni)
          acc[mi][ni] = __builtin_amdgcn_mfma_f32_16x16x32_f16(af[mi], bf[ni],
                                                               acc[mi][ni], 0, 0, 0);
    }
    __syncthreads();
  }
  // C store: frag col = lane&15 (=r), row = 4*q + reg
#pragma unroll
  for (int mi = 0; mi < 4; ++mi)
#pragma unroll
    for (int ni = 0; ni < 4; ++ni)
#pragma unroll
      for (int reg = 0; reg < 4; ++reg) {
        int row = m0 + mi * 16 + q * 4 + reg;
        int col = n0 + ni * 16 + r;
        C[(size_t)row * Nt + col] = acc[mi][ni][reg];
      }
}

// ---------------------------------------------------------------------------
// Kernel 5: Gaussian filter + scale + transpose to AB[f][256] f16.
// AB[f][kap<128] = (cf/512)*filt(k)*Sr_k ; AB[f][kap>=128] = same * Ss_k.
// f16 underflow of filt (<6e-8, i.e. >~5.7 sigma) gives exact-0 truncation.
// ---------------------------------------------------------------------------
__global__ __launch_bounds__(256) void filt_k(const float* __restrict__ Cf,
                                              const float* __restrict__ f0,
                                              const float* __restrict__ nstd,
                                              const float* __restrict__ f0b,
                                              _Float16* __restrict__ AB) {
  const int fbase = blockIdx.x * 64;   // grid 128
  const int tid = threadIdx.x;
  const int fl = tid & 63;
  const int f = fbase + fl;
  const int be = f >> 6;
  __shared__ unsigned int T[64][132];
  const float F0_DIFF = 780.0f / 11025.0f;
  const float mu = f0_to_norm(f0[f], f0b[be]);
  const float sd = fminf(fmaxf(nstd[f], 1e-12f), 1.0f) * F0_DIFF;
  const float inv_sd = 1.0f / sd;

  for (int it = 0; it < 32; ++it) {
    int kp = it * 4 + (tid >> 6);          // kappa-pair 0..127
    int ka = kp * 2, kb = ka + 1;
    float v0 = Cf[(size_t)ka * NFRAMES + f];
    float v1 = Cf[(size_t)kb * NFRAMES + f];
    int k0 = ka & 127, k1 = kb & 127;
    float z0 = ((float)k0 * (1.0f / 256.0f) - mu) * inv_sd;
    float z1 = ((float)k1 * (1.0f / 256.0f) - mu) * inv_sd;
    float s0 = ((k0 == 0) ? 1.0f : 2.0f) * expf(-0.5f * z0 * z0) * (1.0f / 512.0f);
    float s1 = 2.0f * expf(-0.5f * z1 * z1) * (1.0f / 512.0f);   // k1 >= 1 always
    union { _Float16 h[2]; unsigned int u; } p;
    p.h[0] = (_Float16)(v0 * s0);
    p.h[1] = (_Float16)(v1 * s1);
    T[fl][kp] = p.u;
  }
  __syncthreads();
  // write out coalesced: 64 f x 32 granules(16B)
  for (int it = 0; it < 8; ++it) {
    int g = it * 256 + tid;
    int ff = g >> 5, kg = g & 31;
    uint4 o;
    o.x = T[ff][kg * 4 + 0];
    o.y = T[ff][kg * 4 + 1];
    o.z = T[ff][kg * 4 + 2];
    o.w = T[ff][kg * 4 + 3];
    ((uint4*)AB)[(size_t)(fbase + ff) * 32 + kg] = o;
  }
}

// ---------------------------------------------------------------------------
// Kernel 6: oscillator bank + OLA + mix (unchanged from R2).
// ---------------------------------------------------------------------------
__global__ __launch_bounds__(256) void final_k(const float* __restrict__ oenv_g,
                                               const float* __restrict__ oscenv_g,
                                               const float* __restrict__ henv_g,
                                               const float* __restrict__ qphase,
                                               const float* __restrict__ Y,
                                               float* __restrict__ out) {
  const int blk = blockIdx.x;
  const int be = blk >> 2, qtr = blk & 3;
  const int tid = threadIdx.x;
  __shared__ float oenv[SEQ], oscE[SEQ];
  __shared__ __align__(16) float4 qe4[8 * SEQ];
  if (tid < SEQ) {
    oenv[tid] = clip01(oenv_g[be * SEQ + tid]);
    oscE[tid] = clip01(oscenv_g[be * SEQ + tid]);
  }
  __syncthreads();
  for (int idx = tid; idx < 8 * SEQ; idx += 256) {
    int hq = idx >> 6, s = idx & 63;
    const float* hb = henv_g + (size_t)be * (NHARM * SEQ) + (4 * hq) * SEQ + s;
    float e = oscE[s];
    qe4[idx] = make_float4(e * clip01(hb[0]), e * clip01(hb[64]),
                           e * clip01(hb[128]), e * clip01(hb[192]));
  }
  __syncthreads();

  for (int ii = 0; ii < 16; ++ii) {
    const int it = qtr * 16 + ii;
    const int t = it * 256 + tid;
    float pos = ((float)t + 0.5f) * (1.0f / 256.0f) - 0.5f;
    pos = fminf(fmaxf(pos, 0.0f), 63.0f);
    int i0 = (int)pos;
    int i1 = min(i0 + 1, 63);
    float w = pos - (float)i0;

    float q = qphase[(size_t)be * NSAMP + t];
    float x = q * 0.5f;
    float sb = sin_rev(x);
    float cb = cos_rev(x);
    float C = 2.0f * cb;

    float fund = sb * (oscE[i0] * (1.0f - w) + oscE[i1] * w);

    float d0 = 0.0f, d1 = 0.0f;
    float sp = sb;
    float scur = C * sb;
#pragma unroll
    for (int hq = 0; hq < 8; ++hq) {
      float4 qa = qe4[hq * 64 + i0];
      float4 qb = qe4[hq * 64 + i1];
      d0 = fmaf(scur, qa.x, d0); d1 = fmaf(scur, qb.x, d1);
      sp = fmaf(C, scur, -sp);
      d0 = fmaf(sp, qa.y, d0);   d1 = fmaf(sp, qb.y, d1);
      scur = fmaf(C, sp, -scur);
      d0 = fmaf(scur, qa.z, d0); d1 = fmaf(scur, qb.z, d1);
      sp = fmaf(C, scur, -sp);
      d0 = fmaf(sp, qa.w, d0);   d1 = fmaf(sp, qb.w, d1);
      scur = fmaf(C, sp, -scur);
    }
    float osc = fund + d0 * (1.0f - w) + d1 * w;
    float mix = oenv[i0] * (1.0f - w) + oenv[i1] * w;

    float noise = Y[((size_t)be * SEQ + it) * NWS + tid];
    if (it > 0) noise += Y[((size_t)be * SEQ + (it - 1)) * NWS + 256 + tid];

    out[(size_t)be * NSAMP + t] = fmaf(osc, mix, noise * (1.0f - mix));
  }
}

// ---------------------------------------------------------------------------
extern "C" void kernel_launch(void* const* d_in, const int* in_sizes, int n_in,
                              void* d_out, int out_size, void* d_ws, size_t ws_size,
                              hipStream_t stream) {
  const float* f0           = (const float*)d_in[0];
  const float* overall_env  = (const float*)d_in[1];
  const float* osc_env      = (const float*)d_in[2];
  // d_in[3] = noise_env: unused by the reference
  const float* harm_env     = (const float*)d_in[4];
  const float* noise_std    = (const float*)d_in[5];
  const float* f0_base      = (const float*)d_in[6];
  const float* noise_frames = (const float*)d_in[7];
  float* out = (float*)d_out;

  // workspace layout (f32 slots)
  float* qphase = (float*)d_ws;                                   // 2,097,152
  float* Y      = qphase + (size_t)BE * NSAMP;                    // 4,194,304
  float* Cf     = Y + (size_t)NFRAMES * NWS;                      // 2,097,152
  _Float16* XW  = (_Float16*)(Cf + (size_t)256 * NFRAMES);        // 4,194,304 f16
  _Float16* W1  = XW + (size_t)NFRAMES * NWS;                     // 131,072 f16
  _Float16* W2  = W1 + 256 * 512;                                 // 131,072 f16
  _Float16* AB  = W2 + 512 * 256;                                 // 2,097,152 f16

  wgen_k<<<768, 256, 0, stream>>>(W1, W2);
  win_k<<<4096, 256, 0, stream>>>(noise_frames, XW);
  phase_k<<<BE, 256, 0, stream>>>(f0, f0_base, qphase);
  // fwd: C[256][8192] = W1[256][512] x XW[8192][512]^T
  gemm_k<<<dim3(NFRAMES / 128, 256 / 64), 128, 0, stream>>>(W1, XW, Cf, 512, NFRAMES);
  filt_k<<<128, 256, 0, stream>>>(Cf, f0, noise_std, f0_base, AB);
  // inv: Y[8192][512] = AB[8192][256] x W2[512][256]^T
  gemm_k<<<dim3(NWS / 128, NFRAMES / 64), 128, 0, stream>>>(AB, W2, Y, 256, NWS);
  final_k<<<512, 256, 0, stream>>>(overall_env, osc_env, harm_env, qphase, Y, out);
}

// Round 4
// 59.405 us; speedup vs baseline: 1.6360x; 1.6360x over previous
//
#include <hip/hip_runtime.h>
#include <math.h>

// ---- problem constants ----
#define SEQ 64
#define NSAMP 16384
#define NHARM 32
#define NWS 512
#define NSTEP 256
#define BE 128            // B*E = 8*16
#define NFRAMES 8192      // BE * SEQ

typedef _Float16 half8 __attribute__((ext_vector_type(8)));
typedef _Float16 half4v __attribute__((ext_vector_type(4)));
typedef float f32x4 __attribute__((ext_vector_type(4)));

__device__ __forceinline__ float sin_rev(float x) {  // sin(2*pi*x)
  float r; asm("v_sin_f32 %0, %1" : "=v"(r) : "v"(x)); return r;
}
__device__ __forceinline__ float cos_rev(float x) {  // cos(2*pi*x)
  float r; asm("v_cos_f32 %0, %1" : "=v"(r) : "v"(x)); return r;
}
__device__ __forceinline__ float clip01(float v) { return fminf(fmaxf(v, 0.0f), 1.0f); }

__device__ __forceinline__ float f0_to_norm(float f0v, float bl) {
  const float NYQ = 11025.0f;
  const float MIN_F0 = 20.0f / 11025.0f;
  const float F0_DIFF = 780.0f / 11025.0f;
  float v = fminf(fmaxf(f0v, -0.5f), 0.5f);
  float erb = (0.108f * (bl * NYQ) + 24.7f) / NYQ;
  float fv = clip01(bl + v * erb);
  return MIN_F0 + fv * F0_DIFF;
}

// ---------------------------------------------------------------------------
// Kernel 1: per-(b,e) phase scan (unchanged).
// ---------------------------------------------------------------------------
__global__ __launch_bounds__(256) void phase_k(const float* __restrict__ f0,
                                               const float* __restrict__ f0b,
                                               float* __restrict__ qphase) {
  const int be = blockIdx.x;
  const int tid = threadIdx.x;
  __shared__ float f0n_s[SEQ];
  __shared__ double tsum[256];
  __shared__ float qbuf[4096];
  const float bl = f0b[be];
  if (tid < SEQ) f0n_s[tid] = f0_to_norm(f0[be * SEQ + tid], bl);
  __syncthreads();

  double carry = 0.0;
  for (int ch = 0; ch < 4; ++ch) {
    const int base = ch * 4096 + tid * 16;
    float fv[16];
    double loc = 0.0;
#pragma unroll
    for (int i = 0; i < 16; ++i) {
      int t = base + i;
      float pos = ((float)t + 0.5f) * (1.0f / 256.0f) - 0.5f;
      pos = fminf(fmaxf(pos, 0.0f), 63.0f);
      int i0 = (int)pos;
      int i1 = min(i0 + 1, 63);
      float w = pos - (float)i0;
      float fund = f0n_s[i0] * (1.0f - w) + f0n_s[i1] * w;
      fv[i] = fund;
      loc += (double)fund;
    }
    tsum[tid] = loc;
    __syncthreads();
    for (int off = 1; off < 256; off <<= 1) {
      double add = (tid >= off) ? tsum[tid - off] : 0.0;
      __syncthreads();
      tsum[tid] += add;
      __syncthreads();
    }
    double prefix = carry + ((tid > 0) ? tsum[tid - 1] : 0.0);
    double total = tsum[255];
    double run = prefix;
#pragma unroll
    for (int i = 0; i < 16; ++i) {
      run += (double)fv[i];
      double r = run - 2.0 * floor(run * 0.5);   // mod 2 -> [0,2)
      qbuf[tid * 16 + i] = (float)r;
    }
    carry += total;
    __syncthreads();
    for (int i = 0; i < 16; ++i)
      qphase[(size_t)be * NSAMP + ch * 4096 + i * 256 + tid] = qbuf[i * 256 + tid];
    __syncthreads();
  }
}

// ---------------------------------------------------------------------------
// Kernel 2: twiddle tables + per-frame filter coefficients.
// W1[256][512] rows: 0..127 cos(2pi*k*n/512), 128..255 sin.
// W2[512][256]: row n holds [cos(2pi*k*n/512) k<128 | sin(...) k<128].
// Blocks 768..799: fa[f] = 1/(256*sd), fb[f] = mu/sd per frame.
// ---------------------------------------------------------------------------
__global__ __launch_bounds__(256) void wgen_k(_Float16* __restrict__ W1,
                                              _Float16* __restrict__ W2,
                                              const float* __restrict__ f0,
                                              const float* __restrict__ nstd,
                                              const float* __restrict__ f0b,
                                              float* __restrict__ fa,
                                              float* __restrict__ fb) {
  const int bid = blockIdx.x;
  const int tid = threadIdx.x;
  if (bid < 256) {
    const int m = bid, k = m & 127;
    const bool isSin = m >= 128;
    for (int n = tid; n < 512; n += 256) {
      int a = (k * n) & 511;
      float ph = (float)a * (1.0f / 512.0f);
      W1[m * 512 + n] = (_Float16)(isSin ? sin_rev(ph) : cos_rev(ph));
    }
  } else if (bid < 768) {
    const int n = bid - 256;
    const int kap = tid;
    const int k = kap & 127;
    const bool isSin = kap >= 128;
    int a = (k * n) & 511;
    float ph = (float)a * (1.0f / 512.0f);
    W2[n * 256 + kap] = (_Float16)(isSin ? sin_rev(ph) : cos_rev(ph));
  } else {
    const float F0_DIFF = 780.0f / 11025.0f;
    const int f = (bid - 768) * 256 + tid;
    const float mu = f0_to_norm(f0[f], f0b[f >> 6]);
    const float sd = fminf(fmaxf(nstd[f], 1e-12f), 1.0f) * F0_DIFF;
    const float inv_sd = 1.0f / sd;
    fa[f] = inv_sd * (1.0f / 256.0f);
    fb[f] = mu * inv_sd;
  }
}

// ---------------------------------------------------------------------------
// Kernel 3: Hann window + f16 convert (unchanged).
// ---------------------------------------------------------------------------
__global__ __launch_bounds__(256) void win_k(const float* __restrict__ x,
                                             _Float16* __restrict__ xw) {
  const int idx = blockIdx.x * 256 + threadIdx.x;  // float4 index, grid 4096
  float4 v = ((const float4*)x)[idx];
  const int n = (idx * 4) & 511;
  half4v o;
  float w0 = 0.5f - 0.5f * cos_rev((float)(n + 0) * (1.0f / 512.0f));
  float w1 = 0.5f - 0.5f * cos_rev((float)(n + 1) * (1.0f / 512.0f));
  float w2 = 0.5f - 0.5f * cos_rev((float)(n + 2) * (1.0f / 512.0f));
  float w3 = 0.5f - 0.5f * cos_rev((float)(n + 3) * (1.0f / 512.0f));
  o[0] = (_Float16)(v.x * w0);
  o[1] = (_Float16)(v.y * w1);
  o[2] = (_Float16)(v.z * w2);
  o[3] = (_Float16)(v.w * w3);
  ((half4v*)xw)[idx] = o;
}

// ---------------------------------------------------------------------------
// Kernel 4: GEMM v2. C[M][N] = A[M][K] x B[N][K]^T, A/B f16 K-contiguous.
// 256 threads = 4 waves; tile 64x64, BK=64, double-buffered LDS with
// register-staged prefetch. Wave w computes C rows [w*16, w*16+16).
// MODE 0: C = f32 out (inverse DFT -> Y).
// MODE 1: fused Gaussian filter epilogue, f16 out (forward DFT -> AB).
// ---------------------------------------------------------------------------
template <int MODE>
__global__ __launch_bounds__(256) void gemm2_k(const _Float16* __restrict__ A,
                                               const _Float16* __restrict__ B,
                                               void* __restrict__ Cout,
                                               const float* __restrict__ fa,
                                               const float* __restrict__ fb,
                                               int Kt, int Nt) {
  const int bn0 = blockIdx.x * 64;
  const int m0 = blockIdx.y * 64;
  const int tid = threadIdx.x;
  const int wave = tid >> 6, lane = tid & 63;
  const int r = lane & 15, q = lane >> 4;
  __shared__ __align__(16) _Float16 Ash[2][64 * 64];
  __shared__ __align__(16) _Float16 Bsh[2][64 * 64];

  const int nT = Kt >> 6;
  const int srow0 = tid >> 3, srow1 = (256 + tid) >> 3;   // staging rows
  const int skg = tid & 7;                                 // staging granule

  half8 ra[2], rb[2];
  f32x4 acc[4] = {};

  // prologue: load + write tile 0
  {
    const size_t a0 = (size_t)(m0 + srow0) * Kt + skg * 8;
    const size_t a1 = (size_t)(m0 + srow1) * Kt + skg * 8;
    ra[0] = *(const half8*)(A + a0);
    ra[1] = *(const half8*)(A + a1);
    rb[0] = *(const half8*)(B + (size_t)(bn0 + srow0) * Kt + skg * 8);
    rb[1] = *(const half8*)(B + (size_t)(bn0 + srow1) * Kt + skg * 8);
    *(half8*)(&Ash[0][srow0 * 64 + ((skg ^ (srow0 & 7)) << 3)]) = ra[0];
    *(half8*)(&Ash[0][srow1 * 64 + ((skg ^ (srow1 & 7)) << 3)]) = ra[1];
    *(half8*)(&Bsh[0][srow0 * 64 + ((skg ^ (srow0 & 7)) << 3)]) = rb[0];
    *(half8*)(&Bsh[0][srow1 * 64 + ((skg ^ (srow1 & 7)) << 3)]) = rb[1];
  }

  for (int t = 0;;) {
    if (t + 1 < nT) {  // issue next tile's global loads early
      const int kk = (t + 1) << 6;
      ra[0] = *(const half8*)(A + (size_t)(m0 + srow0) * Kt + kk + skg * 8);
      ra[1] = *(const half8*)(A + (size_t)(m0 + srow1) * Kt + kk + skg * 8);
      rb[0] = *(const half8*)(B + (size_t)(bn0 + srow0) * Kt + kk + skg * 8);
      rb[1] = *(const half8*)(B + (size_t)(bn0 + srow1) * Kt + kk + skg * 8);
    }
    __syncthreads();
    const int b = t & 1;
#pragma unroll
    for (int ks = 0; ks < 2; ++ks) {
      const int swz = ((ks * 4 + q) ^ (r & 7)) << 3;
      half8 af = *(const half8*)(&Ash[b][(wave * 16 + r) * 64 + swz]);
      half8 bf0 = *(const half8*)(&Bsh[b][(0 * 16 + r) * 64 + swz]);
      half8 bf1 = *(const half8*)(&Bsh[b][(1 * 16 + r) * 64 + swz]);
      half8 bf2 = *(const half8*)(&Bsh[b][(2 * 16 + r) * 64 + swz]);
      half8 bf3 = *(const half8*)(&Bsh[b][(3 * 16 + r) * 64 + swz]);
      acc[0] = __builtin_amdgcn_mfma_f32_16x16x32_f16(af, bf0, acc[0], 0, 0, 0);
      acc[1] = __builtin_amdgcn_mfma_f32_16x16x32_f16(af, bf1, acc[1], 0, 0, 0);
      acc[2] = __builtin_amdgcn_mfma_f32_16x16x32_f16(af, bf2, acc[2], 0, 0, 0);
      acc[3] = __builtin_amdgcn_mfma_f32_16x16x32_f16(af, bf3, acc[3], 0, 0, 0);
    }
    if (t + 1 >= nT) break;
    __syncthreads();
    const int nb = (t + 1) & 1;
    *(half8*)(&Ash[nb][srow0 * 64 + ((skg ^ (srow0 & 7)) << 3)]) = ra[0];
    *(half8*)(&Ash[nb][srow1 * 64 + ((skg ^ (srow1 & 7)) << 3)]) = ra[1];
    *(half8*)(&Bsh[nb][srow0 * 64 + ((skg ^ (srow0 & 7)) << 3)]) = rb[0];
    *(half8*)(&Bsh[nb][srow1 * 64 + ((skg ^ (srow1 & 7)) << 3)]) = rb[1];
    ++t;
  }

  // epilogue: C frag row = q*4+reg, col = r
  if (MODE == 0) {
    float* C = (float*)Cout;
#pragma unroll
    for (int reg = 0; reg < 4; ++reg) {
      const int row = m0 + wave * 16 + q * 4 + reg;
#pragma unroll
      for (int ni = 0; ni < 4; ++ni)
        C[(size_t)row * Nt + bn0 + ni * 16 + r] = acc[ni][reg];
    }
  } else {
    _Float16* C = (_Float16*)Cout;
#pragma unroll
    for (int reg = 0; reg < 4; ++reg) {
      const int row = m0 + wave * 16 + q * 4 + reg;   // frame
      const float a = fa[row], bmu = fb[row];
#pragma unroll
      for (int ni = 0; ni < 4; ++ni) {
        const int col = bn0 + ni * 16 + r;             // kappa
        const int k = col & 127;
        float z = fmaf((float)k, a, -bmu);
        float cf = (k == 0) ? (1.0f / 512.0f) : (2.0f / 512.0f);
        float s = cf * exp2f(z * z * -0.72134752044f);  // exp(-z^2/2)
        C[(size_t)row * 256 + col] = (_Float16)(acc[ni][reg] * s);
      }
    }
  }
}

// ---------------------------------------------------------------------------
// Kernel 5: oscillator bank (Chebyshev) + OLA + mix (unchanged).
// ---------------------------------------------------------------------------
__global__ __launch_bounds__(256) void final_k(const float* __restrict__ oenv_g,
                                               const float* __restrict__ oscenv_g,
                                               const float* __restrict__ henv_g,
                                               const float* __restrict__ qphase,
                                               const float* __restrict__ Y,
                                               float* __restrict__ out) {
  const int blk = blockIdx.x;
  const int be = blk >> 2, qtr = blk & 3;
  const int tid = threadIdx.x;
  __shared__ float oenv[SEQ], oscE[SEQ];
  __shared__ __align__(16) float4 qe4[8 * SEQ];
  if (tid < SEQ) {
    oenv[tid] = clip01(oenv_g[be * SEQ + tid]);
    oscE[tid] = clip01(oscenv_g[be * SEQ + tid]);
  }
  __syncthreads();
  for (int idx = tid; idx < 8 * SEQ; idx += 256) {
    int hq = idx >> 6, s = idx & 63;
    const float* hb = henv_g + (size_t)be * (NHARM * SEQ) + (4 * hq) * SEQ + s;
    float e = oscE[s];
    qe4[idx] = make_float4(e * clip01(hb[0]), e * clip01(hb[64]),
                           e * clip01(hb[128]), e * clip01(hb[192]));
  }
  __syncthreads();

  for (int ii = 0; ii < 16; ++ii) {
    const int it = qtr * 16 + ii;
    const int t = it * 256 + tid;
    float pos = ((float)t + 0.5f) * (1.0f / 256.0f) - 0.5f;
    pos = fminf(fmaxf(pos, 0.0f), 63.0f);
    int i0 = (int)pos;
    int i1 = min(i0 + 1, 63);
    float w = pos - (float)i0;

    float q = qphase[(size_t)be * NSAMP + t];
    float x = q * 0.5f;
    float sb = sin_rev(x);
    float cb = cos_rev(x);
    float C = 2.0f * cb;

    float fund = sb * (oscE[i0] * (1.0f - w) + oscE[i1] * w);

    float d0 = 0.0f, d1 = 0.0f;
    float sp = sb;
    float scur = C * sb;
#pragma unroll
    for (int hq = 0; hq < 8; ++hq) {
      float4 qa = qe4[hq * 64 + i0];
      float4 qb = qe4[hq * 64 + i1];
      d0 = fmaf(scur, qa.x, d0); d1 = fmaf(scur, qb.x, d1);
      sp = fmaf(C, scur, -sp);
      d0 = fmaf(sp, qa.y, d0);   d1 = fmaf(sp, qb.y, d1);
      scur = fmaf(C, sp, -scur);
      d0 = fmaf(scur, qa.z, d0); d1 = fmaf(scur, qb.z, d1);
      sp = fmaf(C, scur, -sp);
      d0 = fmaf(sp, qa.w, d0);   d1 = fmaf(sp, qb.w, d1);
      scur = fmaf(C, sp, -scur);
    }
    float osc = fund + d0 * (1.0f - w) + d1 * w;
    float mix = oenv[i0] * (1.0f - w) + oenv[i1] * w;

    float noise = Y[((size_t)be * SEQ + it) * NWS + tid];
    if (it > 0) noise += Y[((size_t)be * SEQ + (it - 1)) * NWS + 256 + tid];

    out[(size_t)be * NSAMP + t] = fmaf(osc, mix, noise * (1.0f - mix));
  }
}

// ---------------------------------------------------------------------------
extern "C" void kernel_launch(void* const* d_in, const int* in_sizes, int n_in,
                              void* d_out, int out_size, void* d_ws, size_t ws_size,
                              hipStream_t stream) {
  const float* f0           = (const float*)d_in[0];
  const float* overall_env  = (const float*)d_in[1];
  const float* osc_env      = (const float*)d_in[2];
  // d_in[3] = noise_env: unused by the reference
  const float* harm_env     = (const float*)d_in[4];
  const float* noise_std    = (const float*)d_in[5];
  const float* f0_base      = (const float*)d_in[6];
  const float* noise_frames = (const float*)d_in[7];
  float* out = (float*)d_out;

  // workspace layout
  float* qphase  = (float*)d_ws;                          // 2,097,152 f32
  float* Y       = qphase + (size_t)BE * NSAMP;           // 4,194,304 f32
  _Float16* XW   = (_Float16*)(Y + (size_t)NFRAMES * NWS);// 4,194,304 f16
  _Float16* W1   = XW + (size_t)NFRAMES * NWS;            // 131,072 f16
  _Float16* W2   = W1 + 256 * 512;                        // 131,072 f16
  _Float16* AB   = W2 + 512 * 256;                        // 2,097,152 f16
  float* fa      = (float*)(AB + (size_t)NFRAMES * 256);  // 8,192 f32
  float* fb      = fa + NFRAMES;                          // 8,192 f32

  wgen_k<<<800, 256, 0, stream>>>(W1, W2, f0, noise_std, f0_base, fa, fb);
  win_k<<<4096, 256, 0, stream>>>(noise_frames, XW);
  phase_k<<<BE, 256, 0, stream>>>(f0, f0_base, qphase);
  // fwd: AB[8192][256] = filt( XW[8192][512] x W1[256][512]^T )
  gemm2_k<1><<<dim3(256 / 64, NFRAMES / 64), 256, 0, stream>>>(XW, W1, AB, fa, fb, 512, 256);
  // inv: Y[8192][512] = AB[8192][256] x W2[512][256]^T
  gemm2_k<0><<<dim3(NWS / 64, NFRAMES / 64), 256, 0, stream>>>(AB, W2, Y, nullptr, nullptr, 256, 512);
  final_k<<<512, 256, 0, stream>>>(overall_env, osc_env, harm_env, qphase, Y, out);
}

// Round 5
// 52.912 us; speedup vs baseline: 1.8368x; 1.1227x over previous
//
#include <hip/hip_runtime.h>
#include <math.h>

// ---- problem constants ----
#define SEQ 64
#define NSAMP 16384
#define NHARM 32
#define NWS 512
#define NSTEP 256
#define BE 128            // B*E = 8*16
#define NFRAMES 8192      // BE * SEQ

typedef _Float16 half8 __attribute__((ext_vector_type(8)));
typedef float f32x4 __attribute__((ext_vector_type(4)));

__device__ __forceinline__ float sin_rev(float x) {  // sin(2*pi*x)
  float r; asm("v_sin_f32 %0, %1" : "=v"(r) : "v"(x)); return r;
}
__device__ __forceinline__ float cos_rev(float x) {  // cos(2*pi*x)
  float r; asm("v_cos_f32 %0, %1" : "=v"(r) : "v"(x)); return r;
}
__device__ __forceinline__ float clip01(float v) { return fminf(fmaxf(v, 0.0f), 1.0f); }

__device__ __forceinline__ float f0_to_norm(float f0v, float bl) {
  const float NYQ = 11025.0f;
  const float MIN_F0 = 20.0f / 11025.0f;
  const float F0_DIFF = 780.0f / 11025.0f;
  float v = fminf(fmaxf(f0v, -0.5f), 0.5f);
  float erb = (0.108f * (bl * NYQ) + 24.7f) / NYQ;
  float fv = clip01(bl + v * erb);
  return MIN_F0 + fv * F0_DIFF;
}

// ---------------------------------------------------------------------------
// Kernel 1: fused prep.
//   blocks [0,128):    phase scan per (b,e)  (wave-shuffle f64 scan)
//   blocks [128,384):  W1[256][512] twiddles (cos rows 0..127, sin 128..255)
//   blocks [384,896):  W2[512][256] twiddles (row n: [cos k<128 | sin k<128])
//   blocks [896,928):  fa[f]=1/(256*sd), fb[f]=mu/sd
// ---------------------------------------------------------------------------
__global__ __launch_bounds__(256) void prep_k(const float* __restrict__ f0,
                                              const float* __restrict__ nstd,
                                              const float* __restrict__ f0b,
                                              float* __restrict__ qphase,
                                              _Float16* __restrict__ W1,
                                              _Float16* __restrict__ W2,
                                              float* __restrict__ fa,
                                              float* __restrict__ fb) {
  const int bid = blockIdx.x;
  const int tid = threadIdx.x;

  if (bid < 128) {
    // ---- phase scan ----
    const int be = bid;
    const int lane = tid & 63, wid = tid >> 6;
    __shared__ float f0n_s[SEQ];
    __shared__ double wtot[4];
    __shared__ float qbuf[256][17];          // pad 17: conflict-free
    const float bl = f0b[be];
    if (tid < SEQ) f0n_s[tid] = f0_to_norm(f0[be * SEQ + tid], bl);
    __syncthreads();

    double carry = 0.0;
    for (int ch = 0; ch < 4; ++ch) {
      const int base = ch * 4096 + tid * 16;
      float fv[16];
      double loc = 0.0;
#pragma unroll
      for (int i = 0; i < 16; ++i) {
        int t = base + i;
        float pos = ((float)t + 0.5f) * (1.0f / 256.0f) - 0.5f;
        pos = fminf(fmaxf(pos, 0.0f), 63.0f);
        int i0 = (int)pos;
        int i1 = min(i0 + 1, 63);
        float w = pos - (float)i0;
        float fund = f0n_s[i0] * (1.0f - w) + f0n_s[i1] * w;
        fv[i] = fund;
        loc += (double)fund;
      }
      // intra-wave inclusive shuffle scan (f64), no barriers
      double sc = loc;
#pragma unroll
      for (int off = 1; off < 64; off <<= 1) {
        double u = __shfl_up(sc, off, 64);
        if (lane >= off) sc += u;
      }
      if (lane == 63) wtot[wid] = sc;
      __syncthreads();
      double w0 = wtot[0], w1 = wtot[1], w2 = wtot[2], w3 = wtot[3];
      double woff = carry;
      if (wid > 0) woff += w0;
      if (wid > 1) woff += w1;
      if (wid > 2) woff += w2;
      double run = woff + (sc - loc);        // exclusive prefix for this thread
      carry += w0 + w1 + w2 + w3;
#pragma unroll
      for (int i = 0; i < 16; ++i) {
        run += (double)fv[i];
        double r = run - 2.0 * floor(run * 0.5);   // mod 2 -> [0,2)
        qbuf[tid][i] = (float)r;
      }
      __syncthreads();
      // coalesced copy-out
#pragma unroll
      for (int i = 0; i < 16; ++i) {
        int s = i * 256 + tid;
        qphase[(size_t)be * NSAMP + ch * 4096 + s] = qbuf[s >> 4][s & 15];
      }
    }
  } else if (bid < 384) {
    const int m = bid - 128, k = m & 127;
    const bool isSin = m >= 128;
    for (int n = tid; n < 512; n += 256) {
      int a = (k * n) & 511;
      float ph = (float)a * (1.0f / 512.0f);
      W1[m * 512 + n] = (_Float16)(isSin ? sin_rev(ph) : cos_rev(ph));
    }
  } else if (bid < 896) {
    const int n = bid - 384;
    const int kap = tid;
    const int k = kap & 127;
    const bool isSin = kap >= 128;
    int a = (k * n) & 511;
    float ph = (float)a * (1.0f / 512.0f);
    W2[n * 256 + kap] = (_Float16)(isSin ? sin_rev(ph) : cos_rev(ph));
  } else {
    const float F0_DIFF = 780.0f / 11025.0f;
    const int f = (bid - 896) * 256 + tid;
    const float mu = f0_to_norm(f0[f], f0b[f >> 6]);
    const float sd = fminf(fmaxf(nstd[f], 1e-12f), 1.0f) * F0_DIFF;
    const float inv_sd = 1.0f / sd;
    fa[f] = inv_sd * (1.0f / 256.0f);
    fb[f] = mu * inv_sd;
  }
}

// ---------------------------------------------------------------------------
// Kernel 2: GEMM. C[M][N] = A[M][K] x B[N][K]^T. 256 thr = 4 waves, 64x64
// tile, BK=64, double-buffered LDS, reg-staged prefetch.
// MODE 1 (fwd DFT): A = f32 frames with Hann window fused into staging,
//                   Gaussian-filter epilogue, f16 out (AB).
// MODE 0 (inv DFT): A = f16 AB, f32 out (Y).
// ---------------------------------------------------------------------------
template <int MODE>
__global__ __launch_bounds__(256) void gemm2_k(const float* __restrict__ Af,
                                               const _Float16* __restrict__ Ah,
                                               const _Float16* __restrict__ B,
                                               void* __restrict__ Cout,
                                               const float* __restrict__ fa,
                                               const float* __restrict__ fb,
                                               int Kt, int Nt) {
  const int bn0 = blockIdx.x * 64;
  const int m0 = blockIdx.y * 64;
  const int tid = threadIdx.x;
  const int wave = tid >> 6, lane = tid & 63;
  const int r = lane & 15, q = lane >> 4;
  __shared__ __align__(16) _Float16 Ash[2][64 * 64];
  __shared__ __align__(16) _Float16 Bsh[2][64 * 64];

  const int nT = Kt >> 6;
  const int srow0 = tid >> 3, srow1 = (256 + tid) >> 3;
  const int skg = tid & 7;

  half8 ra[2], rb[2];
  f32x4 acc[4] = {};

  // Hann window for this thread's 8-sample granule (depends on kk; base part
  // n0w = skg*8 + j). Recompute per tile: 8 cos_rev.
  auto load_a = [&](int kk) {
    if (MODE == 1) {
      const float* s0 = Af + (size_t)(m0 + srow0) * Kt + kk + skg * 8;
      const float* s1 = Af + (size_t)(m0 + srow1) * Kt + kk + skg * 8;
      float4 a0 = ((const float4*)s0)[0], a1 = ((const float4*)s0)[1];
      float4 b0 = ((const float4*)s1)[0], b1 = ((const float4*)s1)[1];
      float wv[8];
#pragma unroll
      for (int j = 0; j < 8; ++j)
        wv[j] = 0.5f - 0.5f * cos_rev((float)(kk + skg * 8 + j) * (1.0f / 512.0f));
      ra[0][0] = (_Float16)(a0.x * wv[0]); ra[0][1] = (_Float16)(a0.y * wv[1]);
      ra[0][2] = (_Float16)(a0.z * wv[2]); ra[0][3] = (_Float16)(a0.w * wv[3]);
      ra[0][4] = (_Float16)(a1.x * wv[4]); ra[0][5] = (_Float16)(a1.y * wv[5]);
      ra[0][6] = (_Float16)(a1.z * wv[6]); ra[0][7] = (_Float16)(a1.w * wv[7]);
      ra[1][0] = (_Float16)(b0.x * wv[0]); ra[1][1] = (_Float16)(b0.y * wv[1]);
      ra[1][2] = (_Float16)(b0.z * wv[2]); ra[1][3] = (_Float16)(b0.w * wv[3]);
      ra[1][4] = (_Float16)(b1.x * wv[4]); ra[1][5] = (_Float16)(b1.y * wv[5]);
      ra[1][6] = (_Float16)(b1.z * wv[6]); ra[1][7] = (_Float16)(b1.w * wv[7]);
    } else {
      ra[0] = *(const half8*)(Ah + (size_t)(m0 + srow0) * Kt + kk + skg * 8);
      ra[1] = *(const half8*)(Ah + (size_t)(m0 + srow1) * Kt + kk + skg * 8);
    }
    rb[0] = *(const half8*)(B + (size_t)(bn0 + srow0) * Kt + kk + skg * 8);
    rb[1] = *(const half8*)(B + (size_t)(bn0 + srow1) * Kt + kk + skg * 8);
  };
  auto store_lds = [&](int b) {
    *(half8*)(&Ash[b][srow0 * 64 + ((skg ^ (srow0 & 7)) << 3)]) = ra[0];
    *(half8*)(&Ash[b][srow1 * 64 + ((skg ^ (srow1 & 7)) << 3)]) = ra[1];
    *(half8*)(&Bsh[b][srow0 * 64 + ((skg ^ (srow0 & 7)) << 3)]) = rb[0];
    *(half8*)(&Bsh[b][srow1 * 64 + ((skg ^ (srow1 & 7)) << 3)]) = rb[1];
  };

  load_a(0);
  store_lds(0);

  for (int t = 0;;) {
    if (t + 1 < nT) load_a((t + 1) << 6);
    __syncthreads();
    const int b = t & 1;
#pragma unroll
    for (int ks = 0; ks < 2; ++ks) {
      const int swz = ((ks * 4 + q) ^ (r & 7)) << 3;
      half8 af = *(const half8*)(&Ash[b][(wave * 16 + r) * 64 + swz]);
      half8 bf0 = *(const half8*)(&Bsh[b][(0 * 16 + r) * 64 + swz]);
      half8 bf1 = *(const half8*)(&Bsh[b][(1 * 16 + r) * 64 + swz]);
      half8 bf2 = *(const half8*)(&Bsh[b][(2 * 16 + r) * 64 + swz]);
      half8 bf3 = *(const half8*)(&Bsh[b][(3 * 16 + r) * 64 + swz]);
      acc[0] = __builtin_amdgcn_mfma_f32_16x16x32_f16(af, bf0, acc[0], 0, 0, 0);
      acc[1] = __builtin_amdgcn_mfma_f32_16x16x32_f16(af, bf1, acc[1], 0, 0, 0);
      acc[2] = __builtin_amdgcn_mfma_f32_16x16x32_f16(af, bf2, acc[2], 0, 0, 0);
      acc[3] = __builtin_amdgcn_mfma_f32_16x16x32_f16(af, bf3, acc[3], 0, 0, 0);
    }
    if (t + 1 >= nT) break;
    __syncthreads();
    store_lds((t + 1) & 1);
    ++t;
  }

  if (MODE == 0) {
    float* C = (float*)Cout;
#pragma unroll
    for (int reg = 0; reg < 4; ++reg) {
      const int row = m0 + wave * 16 + q * 4 + reg;
#pragma unroll
      for (int ni = 0; ni < 4; ++ni)
        C[(size_t)row * Nt + bn0 + ni * 16 + r] = acc[ni][reg];
    }
  } else {
    _Float16* C = (_Float16*)Cout;
#pragma unroll
    for (int reg = 0; reg < 4; ++reg) {
      const int row = m0 + wave * 16 + q * 4 + reg;   // frame
      const float a = fa[row], bmu = fb[row];
#pragma unroll
      for (int ni = 0; ni < 4; ++ni) {
        const int col = bn0 + ni * 16 + r;             // kappa
        const int k = col & 127;
        float z = fmaf((float)k, a, -bmu);
        float cf = (k == 0) ? (1.0f / 512.0f) : (2.0f / 512.0f);
        float s = cf * exp2f(z * z * -0.72134752044f);  // exp(-z^2/2)
        C[(size_t)row * 256 + col] = (_Float16)(acc[ni][reg] * s);
      }
    }
  }
}

// ---------------------------------------------------------------------------
// Kernel 3: oscillator bank (Chebyshev) + OLA + mix (unchanged).
// ---------------------------------------------------------------------------
__global__ __launch_bounds__(256) void final_k(const float* __restrict__ oenv_g,
                                               const float* __restrict__ oscenv_g,
                                               const float* __restrict__ henv_g,
                                               const float* __restrict__ qphase,
                                               const float* __restrict__ Y,
                                               float* __restrict__ out) {
  const int blk = blockIdx.x;
  const int be = blk >> 2, qtr = blk & 3;
  const int tid = threadIdx.x;
  __shared__ float oenv[SEQ], oscE[SEQ];
  __shared__ __align__(16) float4 qe4[8 * SEQ];
  if (tid < SEQ) {
    oenv[tid] = clip01(oenv_g[be * SEQ + tid]);
    oscE[tid] = clip01(oscenv_g[be * SEQ + tid]);
  }
  __syncthreads();
  for (int idx = tid; idx < 8 * SEQ; idx += 256) {
    int hq = idx >> 6, s = idx & 63;
    const float* hb = henv_g + (size_t)be * (NHARM * SEQ) + (4 * hq) * SEQ + s;
    float e = oscE[s];
    qe4[idx] = make_float4(e * clip01(hb[0]), e * clip01(hb[64]),
                           e * clip01(hb[128]), e * clip01(hb[192]));
  }
  __syncthreads();

  for (int ii = 0; ii < 16; ++ii) {
    const int it = qtr * 16 + ii;
    const int t = it * 256 + tid;
    float pos = ((float)t + 0.5f) * (1.0f / 256.0f) - 0.5f;
    pos = fminf(fmaxf(pos, 0.0f), 63.0f);
    int i0 = (int)pos;
    int i1 = min(i0 + 1, 63);
    float w = pos - (float)i0;

    float q = qphase[(size_t)be * NSAMP + t];
    float x = q * 0.5f;
    float sb = sin_rev(x);
    float cb = cos_rev(x);
    float C = 2.0f * cb;

    float fund = sb * (oscE[i0] * (1.0f - w) + oscE[i1] * w);

    float d0 = 0.0f, d1 = 0.0f;
    float sp = sb;
    float scur = C * sb;
#pragma unroll
    for (int hq = 0; hq < 8; ++hq) {
      float4 qa = qe4[hq * 64 + i0];
      float4 qb = qe4[hq * 64 + i1];
      d0 = fmaf(scur, qa.x, d0); d1 = fmaf(scur, qb.x, d1);
      sp = fmaf(C, scur, -sp);
      d0 = fmaf(sp, qa.y, d0);   d1 = fmaf(sp, qb.y, d1);
      scur = fmaf(C, sp, -scur);
      d0 = fmaf(scur, qa.z, d0); d1 = fmaf(scur, qb.z, d1);
      sp = fmaf(C, scur, -sp);
      d0 = fmaf(sp, qa.w, d0);   d1 = fmaf(sp, qb.w, d1);
      scur = fmaf(C, sp, -scur);
    }
    float osc = fund + d0 * (1.0f - w) + d1 * w;
    float mix = oenv[i0] * (1.0f - w) + oenv[i1] * w;

    float noise = Y[((size_t)be * SEQ + it) * NWS + tid];
    if (it > 0) noise += Y[((size_t)be * SEQ + (it - 1)) * NWS + 256 + tid];

    out[(size_t)be * NSAMP + t] = fmaf(osc, mix, noise * (1.0f - mix));
  }
}

// ---------------------------------------------------------------------------
extern "C" void kernel_launch(void* const* d_in, const int* in_sizes, int n_in,
                              void* d_out, int out_size, void* d_ws, size_t ws_size,
                              hipStream_t stream) {
  const float* f0           = (const float*)d_in[0];
  const float* overall_env  = (const float*)d_in[1];
  const float* osc_env      = (const float*)d_in[2];
  // d_in[3] = noise_env: unused by the reference
  const float* harm_env     = (const float*)d_in[4];
  const float* noise_std    = (const float*)d_in[5];
  const float* f0_base      = (const float*)d_in[6];
  const float* noise_frames = (const float*)d_in[7];
  float* out = (float*)d_out;

  // workspace layout
  float* qphase  = (float*)d_ws;                          // 2,097,152 f32
  float* Y       = qphase + (size_t)BE * NSAMP;           // 4,194,304 f32
  _Float16* W1   = (_Float16*)(Y + (size_t)NFRAMES * NWS);// 131,072 f16
  _Float16* W2   = W1 + 256 * 512;                        // 131,072 f16
  _Float16* AB   = W2 + 512 * 256;                        // 2,097,152 f16
  float* fa      = (float*)(AB + (size_t)NFRAMES * 256);  // 8,192 f32
  float* fb      = fa + NFRAMES;                          // 8,192 f32

  prep_k<<<928, 256, 0, stream>>>(f0, noise_std, f0_base, qphase, W1, W2, fa, fb);
  // fwd: AB[8192][256] = filt( hann(frames)[8192][512] x W1[256][512]^T )
  gemm2_k<1><<<dim3(256 / 64, NFRAMES / 64), 256, 0, stream>>>(
      noise_frames, nullptr, W1, AB, fa, fb, 512, 256);
  // inv: Y[8192][512] = AB[8192][256] x W2[512][256]^T
  gemm2_k<0><<<dim3(NWS / 64, NFRAMES / 64), 256, 0, stream>>>(
      nullptr, AB, W2, Y, nullptr, nullptr, 256, 512);
  final_k<<<512, 256, 0, stream>>>(overall_env, osc_env, harm_env, qphase, Y, out);
}

// Round 6
// 46.068 us; speedup vs baseline: 2.1097x; 1.1486x over previous
//
#include <hip/hip_runtime.h>
#include <math.h>

// ---- problem constants ----
#define SEQ 64
#define NSAMP 16384
#define NHARM 32
#define NWS 512
#define NSTEP 256
#define BE 128            // B*E = 8*16
#define NFRAMES 8192      // BE * SEQ

typedef _Float16 half8 __attribute__((ext_vector_type(8)));
typedef float f32x4 __attribute__((ext_vector_type(4)));

__device__ __forceinline__ float sin_rev(float x) {  // sin(2*pi*x)
  float r; asm("v_sin_f32 %0, %1" : "=v"(r) : "v"(x)); return r;
}
__device__ __forceinline__ float cos_rev(float x) {  // cos(2*pi*x)
  float r; asm("v_cos_f32 %0, %1" : "=v"(r) : "v"(x)); return r;
}
__device__ __forceinline__ float clip01(float v) { return fminf(fmaxf(v, 0.0f), 1.0f); }

__device__ __forceinline__ float f0_to_norm(float f0v, float bl) {
  const float NYQ = 11025.0f;
  const float MIN_F0 = 20.0f / 11025.0f;
  const float F0_DIFF = 780.0f / 11025.0f;
  float v = fminf(fmaxf(f0v, -0.5f), 0.5f);
  float erb = (0.108f * (bl * NYQ) + 24.7f) / NYQ;
  float fv = clip01(bl + v * erb);
  return MIN_F0 + fv * F0_DIFF;
}

// ---------------------------------------------------------------------------
// Kernel 1: fused prep (unchanged from R5).
//   [0,128):   phase scan per (b,e)
//   [128,384): W1[256][512] twiddles
//   [384,896): W2[512][256] twiddles
//   [896,928): fa[f]=1/(256*sd), fb[f]=mu/sd
// ---------------------------------------------------------------------------
__global__ __launch_bounds__(256) void prep_k(const float* __restrict__ f0,
                                              const float* __restrict__ nstd,
                                              const float* __restrict__ f0b,
                                              float* __restrict__ qphase,
                                              _Float16* __restrict__ W1,
                                              _Float16* __restrict__ W2,
                                              float* __restrict__ fa,
                                              float* __restrict__ fb) {
  const int bid = blockIdx.x;
  const int tid = threadIdx.x;

  if (bid < 128) {
    const int be = bid;
    const int lane = tid & 63, wid = tid >> 6;
    __shared__ float f0n_s[SEQ];
    __shared__ double wtot[4];
    __shared__ float qbuf[256][17];
    const float bl = f0b[be];
    if (tid < SEQ) f0n_s[tid] = f0_to_norm(f0[be * SEQ + tid], bl);
    __syncthreads();

    double carry = 0.0;
    for (int ch = 0; ch < 4; ++ch) {
      const int base = ch * 4096 + tid * 16;
      float fv[16];
      double loc = 0.0;
#pragma unroll
      for (int i = 0; i < 16; ++i) {
        int t = base + i;
        float pos = ((float)t + 0.5f) * (1.0f / 256.0f) - 0.5f;
        pos = fminf(fmaxf(pos, 0.0f), 63.0f);
        int i0 = (int)pos;
        int i1 = min(i0 + 1, 63);
        float w = pos - (float)i0;
        float fund = f0n_s[i0] * (1.0f - w) + f0n_s[i1] * w;
        fv[i] = fund;
        loc += (double)fund;
      }
      double sc = loc;
#pragma unroll
      for (int off = 1; off < 64; off <<= 1) {
        double u = __shfl_up(sc, off, 64);
        if (lane >= off) sc += u;
      }
      if (lane == 63) wtot[wid] = sc;
      __syncthreads();
      double w0 = wtot[0], w1 = wtot[1], w2 = wtot[2], w3 = wtot[3];
      double woff = carry;
      if (wid > 0) woff += w0;
      if (wid > 1) woff += w1;
      if (wid > 2) woff += w2;
      double run = woff + (sc - loc);
      carry += w0 + w1 + w2 + w3;
#pragma unroll
      for (int i = 0; i < 16; ++i) {
        run += (double)fv[i];
        double r = run - 2.0 * floor(run * 0.5);   // mod 2 -> [0,2)
        qbuf[tid][i] = (float)r;
      }
      __syncthreads();
#pragma unroll
      for (int i = 0; i < 16; ++i) {
        int s = i * 256 + tid;
        qphase[(size_t)be * NSAMP + ch * 4096 + s] = qbuf[s >> 4][s & 15];
      }
    }
  } else if (bid < 384) {
    const int m = bid - 128, k = m & 127;
    const bool isSin = m >= 128;
    for (int n = tid; n < 512; n += 256) {
      int a = (k * n) & 511;
      float ph = (float)a * (1.0f / 512.0f);
      W1[m * 512 + n] = (_Float16)(isSin ? sin_rev(ph) : cos_rev(ph));
    }
  } else if (bid < 896) {
    const int n = bid - 384;
    const int kap = tid;
    const int k = kap & 127;
    const bool isSin = kap >= 128;
    int a = (k * n) & 511;
    float ph = (float)a * (1.0f / 512.0f);
    W2[n * 256 + kap] = (_Float16)(isSin ? sin_rev(ph) : cos_rev(ph));
  } else {
    const float F0_DIFF = 780.0f / 11025.0f;
    const int f = (bid - 896) * 256 + tid;
    const float mu = f0_to_norm(f0[f], f0b[f >> 6]);
    const float sd = fminf(fmaxf(nstd[f], 1e-12f), 1.0f) * F0_DIFF;
    const float inv_sd = 1.0f / sd;
    fa[f] = inv_sd * (1.0f / 256.0f);
    fb[f] = mu * inv_sd;
  }
}

// ---------------------------------------------------------------------------
// Kernel 2: forward GEMM (unchanged from R5). AB[8192][256] =
// filt( hann(frames)[8192][512] x W1[256][512]^T ), f16 out.
// ---------------------------------------------------------------------------
__global__ __launch_bounds__(256) void gemmf_k(const float* __restrict__ Af,
                                               const _Float16* __restrict__ B,
                                               _Float16* __restrict__ Cout,
                                               const float* __restrict__ fa,
                                               const float* __restrict__ fb) {
  const int Kt = 512;
  const int bn0 = blockIdx.x * 64;
  const int m0 = blockIdx.y * 64;
  const int tid = threadIdx.x;
  const int wave = tid >> 6, lane = tid & 63;
  const int r = lane & 15, q = lane >> 4;
  __shared__ __align__(16) _Float16 Ash[2][64 * 64];
  __shared__ __align__(16) _Float16 Bsh[2][64 * 64];

  const int nT = Kt >> 6;
  const int srow0 = tid >> 3, srow1 = (256 + tid) >> 3;
  const int skg = tid & 7;

  half8 ra[2], rb[2];
  f32x4 acc[4] = {};

  auto load_a = [&](int kk) {
    const float* s0 = Af + (size_t)(m0 + srow0) * Kt + kk + skg * 8;
    const float* s1 = Af + (size_t)(m0 + srow1) * Kt + kk + skg * 8;
    float4 a0 = ((const float4*)s0)[0], a1 = ((const float4*)s0)[1];
    float4 b0 = ((const float4*)s1)[0], b1 = ((const float4*)s1)[1];
    float wv[8];
#pragma unroll
    for (int j = 0; j < 8; ++j)
      wv[j] = 0.5f - 0.5f * cos_rev((float)(kk + skg * 8 + j) * (1.0f / 512.0f));
    ra[0][0] = (_Float16)(a0.x * wv[0]); ra[0][1] = (_Float16)(a0.y * wv[1]);
    ra[0][2] = (_Float16)(a0.z * wv[2]); ra[0][3] = (_Float16)(a0.w * wv[3]);
    ra[0][4] = (_Float16)(a1.x * wv[4]); ra[0][5] = (_Float16)(a1.y * wv[5]);
    ra[0][6] = (_Float16)(a1.z * wv[6]); ra[0][7] = (_Float16)(a1.w * wv[7]);
    ra[1][0] = (_Float16)(b0.x * wv[0]); ra[1][1] = (_Float16)(b0.y * wv[1]);
    ra[1][2] = (_Float16)(b0.z * wv[2]); ra[1][3] = (_Float16)(b0.w * wv[3]);
    ra[1][4] = (_Float16)(b1.x * wv[4]); ra[1][5] = (_Float16)(b1.y * wv[5]);
    ra[1][6] = (_Float16)(b1.z * wv[6]); ra[1][7] = (_Float16)(b1.w * wv[7]);
    rb[0] = *(const half8*)(B + (size_t)(bn0 + srow0) * Kt + kk + skg * 8);
    rb[1] = *(const half8*)(B + (size_t)(bn0 + srow1) * Kt + kk + skg * 8);
  };
  auto store_lds = [&](int b) {
    *(half8*)(&Ash[b][srow0 * 64 + ((skg ^ (srow0 & 7)) << 3)]) = ra[0];
    *(half8*)(&Ash[b][srow1 * 64 + ((skg ^ (srow1 & 7)) << 3)]) = ra[1];
    *(half8*)(&Bsh[b][srow0 * 64 + ((skg ^ (srow0 & 7)) << 3)]) = rb[0];
    *(half8*)(&Bsh[b][srow1 * 64 + ((skg ^ (srow1 & 7)) << 3)]) = rb[1];
  };

  load_a(0);
  store_lds(0);

  for (int t = 0;;) {
    if (t + 1 < nT) load_a((t + 1) << 6);
    __syncthreads();
    const int b = t & 1;
#pragma unroll
    for (int ks = 0; ks < 2; ++ks) {
      const int swz = ((ks * 4 + q) ^ (r & 7)) << 3;
      half8 af = *(const half8*)(&Ash[b][(wave * 16 + r) * 64 + swz]);
      half8 bf0 = *(const half8*)(&Bsh[b][(0 * 16 + r) * 64 + swz]);
      half8 bf1 = *(const half8*)(&Bsh[b][(1 * 16 + r) * 64 + swz]);
      half8 bf2 = *(const half8*)(&Bsh[b][(2 * 16 + r) * 64 + swz]);
      half8 bf3 = *(const half8*)(&Bsh[b][(3 * 16 + r) * 64 + swz]);
      acc[0] = __builtin_amdgcn_mfma_f32_16x16x32_f16(af, bf0, acc[0], 0, 0, 0);
      acc[1] = __builtin_amdgcn_mfma_f32_16x16x32_f16(af, bf1, acc[1], 0, 0, 0);
      acc[2] = __builtin_amdgcn_mfma_f32_16x16x32_f16(af, bf2, acc[2], 0, 0, 0);
      acc[3] = __builtin_amdgcn_mfma_f32_16x16x32_f16(af, bf3, acc[3], 0, 0, 0);
    }
    if (t + 1 >= nT) break;
    __syncthreads();
    store_lds((t + 1) & 1);
    ++t;
  }

#pragma unroll
  for (int reg = 0; reg < 4; ++reg) {
    const int row = m0 + wave * 16 + q * 4 + reg;   // frame
    const float a = fa[row], bmu = fb[row];
#pragma unroll
    for (int ni = 0; ni < 4; ++ni) {
      const int col = bn0 + ni * 16 + r;             // kappa
      const int k = col & 127;
      float z = fmaf((float)k, a, -bmu);
      float cf = (k == 0) ? (1.0f / 512.0f) : (2.0f / 512.0f);
      float s = cf * exp2f(z * z * -0.72134752044f);  // exp(-z^2/2)
      Cout[(size_t)row * 256 + col] = (_Float16)(acc[ni][reg] * s);
    }
  }
}

// ---------------------------------------------------------------------------
// Kernel 3: fused inverse DFT + overlap-add + oscillator bank + mix.
// noise[gc][n] = AB[gc].W2[n] + AB[gc-1].W2[n+256]  (gc-1 term 0 at chunk 0)
// computed via a 65-row A-tile (row 0 zeroed); epilogue applies the full
// final mix in-register and writes `out` directly. One (b,e) per tile row.
// ---------------------------------------------------------------------------
__global__ __launch_bounds__(256) void invfin_k(const _Float16* __restrict__ AB,
                                                const _Float16* __restrict__ W2,
                                                const float* __restrict__ qphase,
                                                const float* __restrict__ oenv_g,
                                                const float* __restrict__ oscenv_g,
                                                const float* __restrict__ henv_g,
                                                float* __restrict__ out) {
  const int n0 = blockIdx.x * 64;       // sample-within-chunk base (0..192)
  const int m0 = blockIdx.y * 64;       // global chunk base = be*64
  const int be = blockIdx.y;
  const int tid = threadIdx.x;
  const int wave = tid >> 6, lane = tid & 63;
  const int r = lane & 15, q = lane >> 4;

  __shared__ __align__(16) _Float16 Ash[65 * 64];    // rows: AB[m0-1 .. m0+63]
  __shared__ __align__(16) _Float16 B1sh[64 * 64];   // W2[n0+row]
  __shared__ __align__(16) _Float16 B2sh[64 * 64];   // W2[n0+row+256]
  __shared__ __align__(16) float qph_s[64 * 68];     // pitch 68: 2-way max
  __shared__ __align__(16) float4 qe4[8 * SEQ];
  __shared__ float oenv[SEQ], oscE[SEQ];

  if (tid < SEQ) {
    oenv[tid] = clip01(oenv_g[be * SEQ + tid]);
    oscE[tid] = clip01(oscenv_g[be * SEQ + tid]);
  }
  __syncthreads();

  // stage qe4 (osc_env * harm_env), qphase tile, and K-step 0 tiles
  for (int idx = tid; idx < 8 * SEQ; idx += 256) {
    int hq = idx >> 6, s = idx & 63;
    const float* hb = henv_g + (size_t)be * (NHARM * SEQ) + (4 * hq) * SEQ + s;
    float e = oscE[s];
    qe4[idx] = make_float4(e * clip01(hb[0]), e * clip01(hb[64]),
                           e * clip01(hb[128]), e * clip01(hb[192]));
  }
#pragma unroll
  for (int it = 0; it < 4; ++it) {
    int g = it * 256 + tid;              // float4 slot 0..1023
    int row = g >> 4, c4 = g & 15;
    float4 v = *(const float4*)(qphase + (size_t)be * NSAMP + row * 256 + n0 + c4 * 4);
    *(float4*)(&qph_s[row * 68 + c4 * 4]) = v;
  }

  auto stage_AB = [&](int kk) {
    // A: 65 rows x 8 granules = 520 granule-stores
#pragma unroll
    for (int it = 0; it < 3; ++it) {
      int g = it * 256 + tid;
      if (g < 520) {
        int row = g >> 3, kg = g & 7;
        half8 v = {0, 0, 0, 0, 0, 0, 0, 0};
        if (row > 0)
          v = *(const half8*)(AB + (size_t)(m0 - 1 + row) * 256 + kk + kg * 8);
        *(half8*)(&Ash[row * 64 + ((kg ^ (row & 7)) << 3)]) = v;
      }
    }
    // B1 + B2: 2 x 64 rows x 8 granules
#pragma unroll
    for (int it = 0; it < 4; ++it) {
      int g = it * 256 + tid;
      int row = (g >> 3) & 63, kg = g & 7;
      bool second = g >= 512;
      int wrow = n0 + row + (second ? 256 : 0);
      half8 v = *(const half8*)(W2 + (size_t)wrow * 256 + kk + kg * 8);
      _Float16* dst = second ? B2sh : B1sh;
      *(half8*)(&dst[row * 64 + ((kg ^ (row & 7)) << 3)]) = v;
    }
  };

  f32x4 acc[4] = {};
  stage_AB(0);
  __syncthreads();

  for (int t = 0;;) {
#pragma unroll
    for (int ks = 0; ks < 2; ++ks) {
      const int kg = ks * 4 + q;
      const int ra1 = 1 + wave * 16 + r;
      const int ra2 = wave * 16 + r;
      half8 af1 = *(const half8*)(&Ash[ra1 * 64 + ((kg ^ (ra1 & 7)) << 3)]);
      half8 af2 = *(const half8*)(&Ash[ra2 * 64 + ((kg ^ (ra2 & 7)) << 3)]);
#pragma unroll
      for (int ni = 0; ni < 4; ++ni) {
        const int rb = ni * 16 + r;
        const int sw = (kg ^ (rb & 7)) << 3;
        half8 bf1 = *(const half8*)(&B1sh[rb * 64 + sw]);
        half8 bf2 = *(const half8*)(&B2sh[rb * 64 + sw]);
        acc[ni] = __builtin_amdgcn_mfma_f32_16x16x32_f16(af1, bf1, acc[ni], 0, 0, 0);
        acc[ni] = __builtin_amdgcn_mfma_f32_16x16x32_f16(af2, bf2, acc[ni], 0, 0, 0);
      }
    }
    if (t == 3) break;
    __syncthreads();
    stage_AB((t + 1) << 6);
    __syncthreads();
    ++t;
  }

  // epilogue: full final mix, in-register
#pragma unroll
  for (int reg = 0; reg < 4; ++reg) {
    const int c = wave * 16 + q * 4 + reg;           // chunk within be
#pragma unroll
    for (int ni = 0; ni < 4; ++ni) {
      const int n = n0 + ni * 16 + r;
      const int t = c * 256 + n;
      float pos = ((float)t + 0.5f) * (1.0f / 256.0f) - 0.5f;
      pos = fminf(fmaxf(pos, 0.0f), 63.0f);
      int i0 = (int)pos;
      int i1 = min(i0 + 1, 63);
      float w = pos - (float)i0;

      float qv = qph_s[c * 68 + (n - n0)];
      float x = qv * 0.5f;
      float sb = sin_rev(x);
      float cb = cos_rev(x);
      float C = 2.0f * cb;

      float fund = sb * (oscE[i0] * (1.0f - w) + oscE[i1] * w);
      float d0 = 0.0f, d1 = 0.0f;
      float sp = sb;
      float scur = C * sb;
#pragma unroll
      for (int hq = 0; hq < 8; ++hq) {
        float4 qa = qe4[hq * 64 + i0];
        float4 qb = qe4[hq * 64 + i1];
        d0 = fmaf(scur, qa.x, d0); d1 = fmaf(scur, qb.x, d1);
        sp = fmaf(C, scur, -sp);
        d0 = fmaf(sp, qa.y, d0);   d1 = fmaf(sp, qb.y, d1);
        scur = fmaf(C, sp, -scur);
        d0 = fmaf(scur, qa.z, d0); d1 = fmaf(scur, qb.z, d1);
        sp = fmaf(C, scur, -sp);
        d0 = fmaf(sp, qa.w, d0);   d1 = fmaf(sp, qb.w, d1);
        scur = fmaf(C, sp, -scur);
      }
      float osc = fund + d0 * (1.0f - w) + d1 * w;
      float mix = oenv[i0] * (1.0f - w) + oenv[i1] * w;
      out[(size_t)be * NSAMP + t] = fmaf(osc, mix, acc[ni][reg] * (1.0f - mix));
    }
  }
}

// ---------------------------------------------------------------------------
extern "C" void kernel_launch(void* const* d_in, const int* in_sizes, int n_in,
                              void* d_out, int out_size, void* d_ws, size_t ws_size,
                              hipStream_t stream) {
  const float* f0           = (const float*)d_in[0];
  const float* overall_env  = (const float*)d_in[1];
  const float* osc_env      = (const float*)d_in[2];
  // d_in[3] = noise_env: unused by the reference
  const float* harm_env     = (const float*)d_in[4];
  const float* noise_std    = (const float*)d_in[5];
  const float* f0_base      = (const float*)d_in[6];
  const float* noise_frames = (const float*)d_in[7];
  float* out = (float*)d_out;

  // workspace layout
  float* qphase  = (float*)d_ws;                          // 2,097,152 f32
  _Float16* W1   = (_Float16*)(qphase + (size_t)BE * NSAMP); // 131,072 f16
  _Float16* W2   = W1 + 256 * 512;                        // 131,072 f16
  _Float16* AB   = W2 + 512 * 256;                        // 2,097,152 f16
  float* fa      = (float*)(AB + (size_t)NFRAMES * 256);  // 8,192 f32
  float* fb      = fa + NFRAMES;                          // 8,192 f32

  prep_k<<<928, 256, 0, stream>>>(f0, noise_std, f0_base, qphase, W1, W2, fa, fb);
  // fwd: AB[8192][256] = filt( hann(frames)[8192][512] x W1[256][512]^T )
  gemmf_k<<<dim3(4, NFRAMES / 64), 256, 0, stream>>>(noise_frames, W1, AB, fa, fb);
  // inv + OLA + final mix, writes out directly
  invfin_k<<<dim3(4, NFRAMES / 64), 256, 0, stream>>>(
      AB, W2, qphase, overall_env, osc_env, harm_env, out);
}

// Round 7
// 42.711 us; speedup vs baseline: 2.2755x; 1.0786x over previous
//
#include <hip/hip_runtime.h>
#include <math.h>

// ---- problem constants ----
#define SEQ 64
#define NSAMP 16384
#define NHARM 32
#define NWS 512
#define NSTEP 256
#define BE 128            // B*E = 8*16
#define NFRAMES 8192      // BE * SEQ

typedef _Float16 half8 __attribute__((ext_vector_type(8)));
typedef float f32x4 __attribute__((ext_vector_type(4)));

__device__ __forceinline__ float sin_rev(float x) {  // sin(2*pi*x)
  float r; asm("v_sin_f32 %0, %1" : "=v"(r) : "v"(x)); return r;
}
__device__ __forceinline__ float cos_rev(float x) {  // cos(2*pi*x)
  float r; asm("v_cos_f32 %0, %1" : "=v"(r) : "v"(x)); return r;
}
__device__ __forceinline__ float clip01(float v) { return fminf(fmaxf(v, 0.0f), 1.0f); }

__device__ __forceinline__ float f0_to_norm(float f0v, float bl) {
  const float NYQ = 11025.0f;
  const float MIN_F0 = 20.0f / 11025.0f;
  const float F0_DIFF = 780.0f / 11025.0f;
  float v = fminf(fmaxf(f0v, -0.5f), 0.5f);
  float erb = (0.108f * (bl * NYQ) + 24.7f) / NYQ;
  float fv = clip01(bl + v * erb);
  return MIN_F0 + fv * F0_DIFF;
}

// ---------------------------------------------------------------------------
// Kernel 1: prep (twiddles + filter coefs only; phase scan is gone).
//   [0,256):   W1[256][512] twiddles (cos rows 0..127, sin 128..255)
//   [256,768): W2[512][256] twiddles (row n: [cos k<128 | sin k<128])
//   [768,800): fa[f]=1/(256*sd), fb[f]=mu/sd
// ---------------------------------------------------------------------------
__global__ __launch_bounds__(256) void prep_k(const float* __restrict__ f0,
                                              const float* __restrict__ nstd,
                                              const float* __restrict__ f0b,
                                              _Float16* __restrict__ W1,
                                              _Float16* __restrict__ W2,
                                              float* __restrict__ fa,
                                              float* __restrict__ fb) {
  const int bid = blockIdx.x;
  const int tid = threadIdx.x;

  if (bid < 256) {
    const int m = bid, k = m & 127;
    const bool isSin = m >= 128;
    for (int n = tid; n < 512; n += 256) {
      int a = (k * n) & 511;
      float ph = (float)a * (1.0f / 512.0f);
      W1[m * 512 + n] = (_Float16)(isSin ? sin_rev(ph) : cos_rev(ph));
    }
  } else if (bid < 768) {
    const int n = bid - 256;
    const int kap = tid;
    const int k = kap & 127;
    const bool isSin = kap >= 128;
    int a = (k * n) & 511;
    float ph = (float)a * (1.0f / 512.0f);
    W2[n * 256 + kap] = (_Float16)(isSin ? sin_rev(ph) : cos_rev(ph));
  } else {
    const float F0_DIFF = 780.0f / 11025.0f;
    const int f = (bid - 768) * 256 + tid;
    const float mu = f0_to_norm(f0[f], f0b[f >> 6]);
    const float sd = fminf(fmaxf(nstd[f], 1e-12f), 1.0f) * F0_DIFF;
    const float inv_sd = 1.0f / sd;
    fa[f] = inv_sd * (1.0f / 256.0f);
    fb[f] = mu * inv_sd;
  }
}

// ---------------------------------------------------------------------------
// Kernel 2: forward GEMM. AB[8192][256] =
// filt( hann(frames)[8192][512] x W1[256][512]^T ), f16 out.
// Hann weights come from a per-block LDS table (trig computed once).
// ---------------------------------------------------------------------------
__global__ __launch_bounds__(256) void gemmf_k(const float* __restrict__ Af,
                                               const _Float16* __restrict__ B,
                                               _Float16* __restrict__ Cout,
                                               const float* __restrict__ fa,
                                               const float* __restrict__ fb) {
  const int Kt = 512;
  const int bn0 = blockIdx.x * 64;
  const int m0 = blockIdx.y * 64;
  const int tid = threadIdx.x;
  const int wave = tid >> 6, lane = tid & 63;
  const int r = lane & 15, q = lane >> 4;
  __shared__ __align__(16) _Float16 Ash[2][64 * 64];
  __shared__ __align__(16) _Float16 Bsh[2][64 * 64];
  __shared__ __align__(16) float whann[512];

  const int nT = Kt >> 6;
  const int srow0 = tid >> 3, srow1 = (256 + tid) >> 3;
  const int skg = tid & 7;

  half8 ra[2], rb[2];
  f32x4 acc[4] = {};

  whann[tid] = 0.5f - 0.5f * cos_rev((float)tid * (1.0f / 512.0f));
  whann[tid + 256] = 0.5f - 0.5f * cos_rev((float)(tid + 256) * (1.0f / 512.0f));
  __syncthreads();

  auto load_a = [&](int kk) {
    const float* s0 = Af + (size_t)(m0 + srow0) * Kt + kk + skg * 8;
    const float* s1 = Af + (size_t)(m0 + srow1) * Kt + kk + skg * 8;
    float4 a0 = ((const float4*)s0)[0], a1 = ((const float4*)s0)[1];
    float4 b0 = ((const float4*)s1)[0], b1 = ((const float4*)s1)[1];
    float4 w0 = *(const float4*)(&whann[kk + skg * 8]);
    float4 w1 = *(const float4*)(&whann[kk + skg * 8 + 4]);
    ra[0][0] = (_Float16)(a0.x * w0.x); ra[0][1] = (_Float16)(a0.y * w0.y);
    ra[0][2] = (_Float16)(a0.z * w0.z); ra[0][3] = (_Float16)(a0.w * w0.w);
    ra[0][4] = (_Float16)(a1.x * w1.x); ra[0][5] = (_Float16)(a1.y * w1.y);
    ra[0][6] = (_Float16)(a1.z * w1.z); ra[0][7] = (_Float16)(a1.w * w1.w);
    ra[1][0] = (_Float16)(b0.x * w0.x); ra[1][1] = (_Float16)(b0.y * w0.y);
    ra[1][2] = (_Float16)(b0.z * w0.z); ra[1][3] = (_Float16)(b0.w * w0.w);
    ra[1][4] = (_Float16)(b1.x * w1.x); ra[1][5] = (_Float16)(b1.y * w1.y);
    ra[1][6] = (_Float16)(b1.z * w1.z); ra[1][7] = (_Float16)(b1.w * w1.w);
    rb[0] = *(const half8*)(B + (size_t)(bn0 + srow0) * Kt + kk + skg * 8);
    rb[1] = *(const half8*)(B + (size_t)(bn0 + srow1) * Kt + kk + skg * 8);
  };
  auto store_lds = [&](int b) {
    *(half8*)(&Ash[b][srow0 * 64 + ((skg ^ (srow0 & 7)) << 3)]) = ra[0];
    *(half8*)(&Ash[b][srow1 * 64 + ((skg ^ (srow1 & 7)) << 3)]) = ra[1];
    *(half8*)(&Bsh[b][srow0 * 64 + ((skg ^ (srow0 & 7)) << 3)]) = rb[0];
    *(half8*)(&Bsh[b][srow1 * 64 + ((skg ^ (srow1 & 7)) << 3)]) = rb[1];
  };

  load_a(0);
  store_lds(0);

  for (int t = 0;;) {
    if (t + 1 < nT) load_a((t + 1) << 6);
    __syncthreads();
    const int b = t & 1;
#pragma unroll
    for (int ks = 0; ks < 2; ++ks) {
      const int swz = ((ks * 4 + q) ^ (r & 7)) << 3;
      half8 af = *(const half8*)(&Ash[b][(wave * 16 + r) * 64 + swz]);
      half8 bf0 = *(const half8*)(&Bsh[b][(0 * 16 + r) * 64 + swz]);
      half8 bf1 = *(const half8*)(&Bsh[b][(1 * 16 + r) * 64 + swz]);
      half8 bf2 = *(const half8*)(&Bsh[b][(2 * 16 + r) * 64 + swz]);
      half8 bf3 = *(const half8*)(&Bsh[b][(3 * 16 + r) * 64 + swz]);
      acc[0] = __builtin_amdgcn_mfma_f32_16x16x32_f16(af, bf0, acc[0], 0, 0, 0);
      acc[1] = __builtin_amdgcn_mfma_f32_16x16x32_f16(af, bf1, acc[1], 0, 0, 0);
      acc[2] = __builtin_amdgcn_mfma_f32_16x16x32_f16(af, bf2, acc[2], 0, 0, 0);
      acc[3] = __builtin_amdgcn_mfma_f32_16x16x32_f16(af, bf3, acc[3], 0, 0, 0);
    }
    if (t + 1 >= nT) break;
    __syncthreads();
    store_lds((t + 1) & 1);
    ++t;
  }

#pragma unroll
  for (int reg = 0; reg < 4; ++reg) {
    const int row = m0 + wave * 16 + q * 4 + reg;   // frame
    const float a = fa[row], bmu = fb[row];
#pragma unroll
    for (int ni = 0; ni < 4; ++ni) {
      const int col = bn0 + ni * 16 + r;             // kappa
      const int k = col & 127;
      float z = fmaf((float)k, a, -bmu);
      float cf = (k == 0) ? (1.0f / 512.0f) : (2.0f / 512.0f);
      float s = cf * exp2f(z * z * -0.72134752044f);  // exp(-z^2/2)
      Cout[(size_t)row * 256 + col] = (_Float16)(acc[ni][reg] * s);
    }
  }
}

// ---------------------------------------------------------------------------
// Kernel 3: fused inverse DFT + overlap-add + oscillator bank + mix.
// Phase comes from the CLOSED FORM of cumsum(lin_interp(f0n)):
//   t<128:              P = (t+1)*F[0]
//   t=128+256s+u:       P = C[s] + (u+1)*F[s] + D[s]*(u+1)^2/512
//   C[s] = 128F[0] + sum_{m<s} 128*(F[m]+F[m+1])   (f64 wave scan, mod 2)
// ---------------------------------------------------------------------------
__global__ __launch_bounds__(256) void invfin_k(const _Float16* __restrict__ AB,
                                                const _Float16* __restrict__ W2,
                                                const float* __restrict__ f0,
                                                const float* __restrict__ f0b,
                                                const float* __restrict__ oenv_g,
                                                const float* __restrict__ oscenv_g,
                                                const float* __restrict__ henv_g,
                                                float* __restrict__ out) {
  const int n0 = blockIdx.x * 64;       // sample-within-chunk base (0..192)
  const int m0 = blockIdx.y * 64;       // global chunk base = be*64
  const int be = blockIdx.y;
  const int tid = threadIdx.x;
  const int wave = tid >> 6, lane = tid & 63;
  const int r = lane & 15, q = lane >> 4;

  __shared__ __align__(16) _Float16 Ash[65 * 64];    // rows: AB[m0-1 .. m0+63]
  __shared__ __align__(16) _Float16 B1sh[64 * 64];   // W2[n0+row]
  __shared__ __align__(16) _Float16 B2sh[64 * 64];   // W2[n0+row+256]
  __shared__ __align__(16) float4 qe4[8 * SEQ];
  __shared__ float oenv[SEQ], oscE[SEQ];
  __shared__ float Fs[SEQ], Ds[SEQ], Gs[SEQ];

  if (tid < SEQ) {
    oenv[tid] = clip01(oenv_g[be * SEQ + tid]);
    oscE[tid] = clip01(oscenv_g[be * SEQ + tid]);
    Fs[tid] = f0_to_norm(f0[be * SEQ + tid], f0b[be]);
  }
  __syncthreads();

  // wave 0: segment phase-prefix scan (f64, 6 shuffle steps), mod 2
  if (tid < SEQ) {
    const int s = tid;
    float fcur = Fs[s];
    float fnxt = (s < 63) ? Fs[s + 1] : Fs[63];
    Ds[s] = fnxt - fcur;                               // D[63] = 0
    double term = 128.0 * ((double)fcur + (double)fnxt);
    double sc = term;
#pragma unroll
    for (int off = 1; off < 64; off <<= 1) {
      double u = __shfl_up(sc, off, 64);
      if (s >= off) sc += u;
    }
    double C = 128.0 * (double)Fs[0] + (sc - term);    // exclusive prefix
    Gs[s] = (float)(C - 2.0 * floor(C * 0.5));
  }

  // stage qe4 (osc_env * harm_env) and K-step 0 tiles
  for (int idx = tid; idx < 8 * SEQ; idx += 256) {
    int hq = idx >> 6, s = idx & 63;
    const float* hb = henv_g + (size_t)be * (NHARM * SEQ) + (4 * hq) * SEQ + s;
    float e = oscE[s];
    qe4[idx] = make_float4(e * clip01(hb[0]), e * clip01(hb[64]),
                           e * clip01(hb[128]), e * clip01(hb[192]));
  }

  auto stage_AB = [&](int kk) {
#pragma unroll
    for (int it = 0; it < 3; ++it) {
      int g = it * 256 + tid;
      if (g < 520) {
        int row = g >> 3, kg = g & 7;
        half8 v = {0, 0, 0, 0, 0, 0, 0, 0};
        if (row > 0)
          v = *(const half8*)(AB + (size_t)(m0 - 1 + row) * 256 + kk + kg * 8);
        *(half8*)(&Ash[row * 64 + ((kg ^ (row & 7)) << 3)]) = v;
      }
    }
#pragma unroll
    for (int it = 0; it < 4; ++it) {
      int g = it * 256 + tid;
      int row = (g >> 3) & 63, kg = g & 7;
      bool second = g >= 512;
      int wrow = n0 + row + (second ? 256 : 0);
      half8 v = *(const half8*)(W2 + (size_t)wrow * 256 + kk + kg * 8);
      _Float16* dst = second ? B2sh : B1sh;
      *(half8*)(&dst[row * 64 + ((kg ^ (row & 7)) << 3)]) = v;
    }
  };

  f32x4 acc[4] = {};
  stage_AB(0);
  __syncthreads();

  for (int t = 0;;) {
#pragma unroll
    for (int ks = 0; ks < 2; ++ks) {
      const int kg = ks * 4 + q;
      const int ra1 = 1 + wave * 16 + r;
      const int ra2 = wave * 16 + r;
      half8 af1 = *(const half8*)(&Ash[ra1 * 64 + ((kg ^ (ra1 & 7)) << 3)]);
      half8 af2 = *(const half8*)(&Ash[ra2 * 64 + ((kg ^ (ra2 & 7)) << 3)]);
#pragma unroll
      for (int ni = 0; ni < 4; ++ni) {
        const int rb = ni * 16 + r;
        const int sw = (kg ^ (rb & 7)) << 3;
        half8 bf1 = *(const half8*)(&B1sh[rb * 64 + sw]);
        half8 bf2 = *(const half8*)(&B2sh[rb * 64 + sw]);
        acc[ni] = __builtin_amdgcn_mfma_f32_16x16x32_f16(af1, bf1, acc[ni], 0, 0, 0);
        acc[ni] = __builtin_amdgcn_mfma_f32_16x16x32_f16(af2, bf2, acc[ni], 0, 0, 0);
      }
    }
    if (t == 3) break;
    __syncthreads();
    stage_AB((t + 1) << 6);
    __syncthreads();
    ++t;
  }

  // epilogue: analytic phase + oscillator bank + mix, in-register
#pragma unroll
  for (int reg = 0; reg < 4; ++reg) {
    const int c = wave * 16 + q * 4 + reg;           // chunk within be
#pragma unroll
    for (int ni = 0; ni < 4; ++ni) {
      const int n = n0 + ni * 16 + r;
      const int t = c * 256 + n;
      float pos = ((float)t + 0.5f) * (1.0f / 256.0f) - 0.5f;
      pos = fminf(fmaxf(pos, 0.0f), 63.0f);
      int i0 = (int)pos;
      int i1 = min(i0 + 1, 63);
      float w = pos - (float)i0;

      float p;
      if (t < 128) {
        p = (float)(t + 1) * Fs[0];
      } else {
        int s = (t - 128) >> 8;
        float u1 = (float)((t - 128) - (s << 8) + 1);
        p = Gs[s] + fmaf(Ds[s] * (1.0f / 512.0f), u1 * u1, u1 * Fs[s]);
      }
      p = p - 2.0f * floorf(p * 0.5f);               // phase mod 2 (pi units)
      float x = p * 0.5f;
      float sb = sin_rev(x);
      float cb = cos_rev(x);
      float C = 2.0f * cb;

      float fund = sb * (oscE[i0] * (1.0f - w) + oscE[i1] * w);
      float d0 = 0.0f, d1 = 0.0f;
      float sp = sb;
      float scur = C * sb;
#pragma unroll
      for (int hq = 0; hq < 8; ++hq) {
        float4 qa = qe4[hq * 64 + i0];
        float4 qb = qe4[hq * 64 + i1];
        d0 = fmaf(scur, qa.x, d0); d1 = fmaf(scur, qb.x, d1);
        sp = fmaf(C, scur, -sp);
        d0 = fmaf(sp, qa.y, d0);   d1 = fmaf(sp, qb.y, d1);
        scur = fmaf(C, sp, -scur);
        d0 = fmaf(scur, qa.z, d0); d1 = fmaf(scur, qb.z, d1);
        sp = fmaf(C, scur, -sp);
        d0 = fmaf(sp, qa.w, d0);   d1 = fmaf(sp, qb.w, d1);
        scur = fmaf(C, sp, -scur);
      }
      float osc = fund + d0 * (1.0f - w) + d1 * w;
      float mix = oenv[i0] * (1.0f - w) + oenv[i1] * w;
      out[(size_t)be * NSAMP + t] = fmaf(osc, mix, acc[ni][reg] * (1.0f - mix));
    }
  }
}

// ---------------------------------------------------------------------------
extern "C" void kernel_launch(void* const* d_in, const int* in_sizes, int n_in,
                              void* d_out, int out_size, void* d_ws, size_t ws_size,
                              hipStream_t stream) {
  const float* f0           = (const float*)d_in[0];
  const float* overall_env  = (const float*)d_in[1];
  const float* osc_env      = (const float*)d_in[2];
  // d_in[3] = noise_env: unused by the reference
  const float* harm_env     = (const float*)d_in[4];
  const float* noise_std    = (const float*)d_in[5];
  const float* f0_base      = (const float*)d_in[6];
  const float* noise_frames = (const float*)d_in[7];
  float* out = (float*)d_out;

  // workspace layout
  _Float16* W1 = (_Float16*)d_ws;                         // 131,072 f16
  _Float16* W2 = W1 + 256 * 512;                          // 131,072 f16
  _Float16* AB = W2 + 512 * 256;                          // 2,097,152 f16
  float* fa    = (float*)(AB + (size_t)NFRAMES * 256);    // 8,192 f32
  float* fb    = fa + NFRAMES;                            // 8,192 f32

  prep_k<<<800, 256, 0, stream>>>(f0, noise_std, f0_base, W1, W2, fa, fb);
  // fwd: AB[8192][256] = filt( hann(frames)[8192][512] x W1[256][512]^T )
  gemmf_k<<<dim3(4, NFRAMES / 64), 256, 0, stream>>>(noise_frames, W1, AB, fa, fb);
  // inv + OLA + oscillator bank + final mix, writes out directly
  invfin_k<<<dim3(4, NFRAMES / 64), 256, 0, stream>>>(
      AB, W2, f0, f0_base, overall_env, osc_env, harm_env, out);
}

// Round 8
// 36.952 us; speedup vs baseline: 2.6301x; 1.1558x over previous
//
#include <hip/hip_runtime.h>
#include <math.h>

// ---- problem constants ----
#define SEQ 64
#define NSAMP 16384
#define NHARM 32
#define NWS 512
#define NSTEP 256
#define BE 128            // B*E = 8*16
#define NFRAMES 8192      // BE * SEQ

typedef _Float16 half8 __attribute__((ext_vector_type(8)));
typedef float f32x4 __attribute__((ext_vector_type(4)));

__device__ __forceinline__ float sin_rev(float x) {  // sin(2*pi*x)
  float r; asm("v_sin_f32 %0, %1" : "=v"(r) : "v"(x)); return r;
}
__device__ __forceinline__ float cos_rev(float x) {  // cos(2*pi*x)
  float r; asm("v_cos_f32 %0, %1" : "=v"(r) : "v"(x)); return r;
}
__device__ __forceinline__ float clip01(float v) { return fminf(fmaxf(v, 0.0f), 1.0f); }

__device__ __forceinline__ float f0_to_norm(float f0v, float bl) {
  const float NYQ = 11025.0f;
  const float MIN_F0 = 20.0f / 11025.0f;
  const float F0_DIFF = 780.0f / 11025.0f;
  float v = fminf(fmaxf(f0v, -0.5f), 0.5f);
  float erb = (0.108f * (bl * NYQ) + 24.7f) / NYQ;
  float fv = clip01(bl + v * erb);
  return MIN_F0 + fv * F0_DIFF;
}

// ---------------------------------------------------------------------------
// Kernel 1: prep — W1 twiddles only (256 blocks).
// W1[256][512]: rows 0..127 cos(2pi*k*n/512), rows 128..255 sin.
// ---------------------------------------------------------------------------
__global__ __launch_bounds__(256) void prep_k(_Float16* __restrict__ W1) {
  const int m = blockIdx.x, k = m & 127;
  const int tid = threadIdx.x;
  const bool isSin = m >= 128;
  for (int n = tid; n < 512; n += 256) {
    int a = (k * n) & 511;
    float ph = (float)a * (1.0f / 512.0f);
    W1[m * 512 + n] = (_Float16)(isSin ? sin_rev(ph) : cos_rev(ph));
  }
}

// ---------------------------------------------------------------------------
// Kernel 2: forward GEMM + W2 table generation.
//   blocks [0,256):  W2[512][256] twiddles, 2 rows per block (consumer is the
//                    NEXT launch -> no intra-launch race).
//   blocks [256,768): AB[8192][256] = filt( hann(frames) x W1^T ), f16 out.
//     XCD-chunked swizzle: the 4 bn-blocks of one 64-frame stripe share the
//     same physical index mod 8 -> same XCD -> A re-reads are L2 hits.
//     Gaussian-filter coefs (mu/sd) computed inline in the epilogue.
// ---------------------------------------------------------------------------
__global__ __launch_bounds__(256) void gemmf_k(const float* __restrict__ Af,
                                               const _Float16* __restrict__ B,
                                               _Float16* __restrict__ Cout,
                                               _Float16* __restrict__ W2,
                                               const float* __restrict__ f0,
                                               const float* __restrict__ nstd,
                                               const float* __restrict__ f0b) {
  const int tid = threadIdx.x;

  if (blockIdx.x < 256) {   // ---- W2 generation ----
    const int k = tid & 127;
    const bool isSin = tid >= 128;
#pragma unroll
    for (int rr = 0; rr < 2; ++rr) {
      const int n = blockIdx.x * 2 + rr;
      int a = (k * n) & 511;
      float ph = (float)a * (1.0f / 512.0f);
      W2[n * 256 + tid] = (_Float16)(isSin ? sin_rev(ph) : cos_rev(ph));
    }
    return;
  }

  // ---- GEMM: swizzled block decode ----
  const int p = blockIdx.x - 256;          // [0,512)
  const int x = p & 7, j = p >> 3;
  const int mstripe = ((j >> 2) << 3) + x; // [0,128)
  const int bn0 = (j & 3) * 64;
  const int m0 = mstripe * 64;

  const int Kt = 512;
  const int wave = tid >> 6, lane = tid & 63;
  const int r = lane & 15, q = lane >> 4;
  __shared__ __align__(16) _Float16 Ash[2][64 * 64];
  __shared__ __align__(16) _Float16 Bsh[2][64 * 64];
  __shared__ __align__(16) float whann[512];

  const int nT = Kt >> 6;
  const int srow0 = tid >> 3, srow1 = (256 + tid) >> 3;
  const int skg = tid & 7;

  half8 ra[2], rb[2];
  f32x4 acc[4] = {};

  whann[tid] = 0.5f - 0.5f * cos_rev((float)tid * (1.0f / 512.0f));
  whann[tid + 256] = 0.5f - 0.5f * cos_rev((float)(tid + 256) * (1.0f / 512.0f));
  __syncthreads();

  auto load_a = [&](int kk) {
    const float* s0 = Af + (size_t)(m0 + srow0) * Kt + kk + skg * 8;
    const float* s1 = Af + (size_t)(m0 + srow1) * Kt + kk + skg * 8;
    float4 a0 = ((const float4*)s0)[0], a1 = ((const float4*)s0)[1];
    float4 b0 = ((const float4*)s1)[0], b1 = ((const float4*)s1)[1];
    float4 w0 = *(const float4*)(&whann[kk + skg * 8]);
    float4 w1 = *(const float4*)(&whann[kk + skg * 8 + 4]);
    ra[0][0] = (_Float16)(a0.x * w0.x); ra[0][1] = (_Float16)(a0.y * w0.y);
    ra[0][2] = (_Float16)(a0.z * w0.z); ra[0][3] = (_Float16)(a0.w * w0.w);
    ra[0][4] = (_Float16)(a1.x * w1.x); ra[0][5] = (_Float16)(a1.y * w1.y);
    ra[0][6] = (_Float16)(a1.z * w1.z); ra[0][7] = (_Float16)(a1.w * w1.w);
    ra[1][0] = (_Float16)(b0.x * w0.x); ra[1][1] = (_Float16)(b0.y * w0.y);
    ra[1][2] = (_Float16)(b0.z * w0.z); ra[1][3] = (_Float16)(b0.w * w0.w);
    ra[1][4] = (_Float16)(b1.x * w1.x); ra[1][5] = (_Float16)(b1.y * w1.y);
    ra[1][6] = (_Float16)(b1.z * w1.z); ra[1][7] = (_Float16)(b1.w * w1.w);
    rb[0] = *(const half8*)(B + (size_t)(bn0 + srow0) * Kt + kk + skg * 8);
    rb[1] = *(const half8*)(B + (size_t)(bn0 + srow1) * Kt + kk + skg * 8);
  };
  auto store_lds = [&](int b) {
    *(half8*)(&Ash[b][srow0 * 64 + ((skg ^ (srow0 & 7)) << 3)]) = ra[0];
    *(half8*)(&Ash[b][srow1 * 64 + ((skg ^ (srow1 & 7)) << 3)]) = ra[1];
    *(half8*)(&Bsh[b][srow0 * 64 + ((skg ^ (srow0 & 7)) << 3)]) = rb[0];
    *(half8*)(&Bsh[b][srow1 * 64 + ((skg ^ (srow1 & 7)) << 3)]) = rb[1];
  };

  load_a(0);
  store_lds(0);

  for (int t = 0;;) {
    if (t + 1 < nT) load_a((t + 1) << 6);
    __syncthreads();
    const int b = t & 1;
#pragma unroll
    for (int ks = 0; ks < 2; ++ks) {
      const int swz = ((ks * 4 + q) ^ (r & 7)) << 3;
      half8 af = *(const half8*)(&Ash[b][(wave * 16 + r) * 64 + swz]);
      half8 bf0 = *(const half8*)(&Bsh[b][(0 * 16 + r) * 64 + swz]);
      half8 bf1 = *(const half8*)(&Bsh[b][(1 * 16 + r) * 64 + swz]);
      half8 bf2 = *(const half8*)(&Bsh[b][(2 * 16 + r) * 64 + swz]);
      half8 bf3 = *(const half8*)(&Bsh[b][(3 * 16 + r) * 64 + swz]);
      acc[0] = __builtin_amdgcn_mfma_f32_16x16x32_f16(af, bf0, acc[0], 0, 0, 0);
      acc[1] = __builtin_amdgcn_mfma_f32_16x16x32_f16(af, bf1, acc[1], 0, 0, 0);
      acc[2] = __builtin_amdgcn_mfma_f32_16x16x32_f16(af, bf2, acc[2], 0, 0, 0);
      acc[3] = __builtin_amdgcn_mfma_f32_16x16x32_f16(af, bf3, acc[3], 0, 0, 0);
    }
    if (t + 1 >= nT) break;
    __syncthreads();
    store_lds((t + 1) & 1);
    ++t;
  }

  const float F0_DIFF = 780.0f / 11025.0f;
#pragma unroll
  for (int reg = 0; reg < 4; ++reg) {
    const int row = m0 + wave * 16 + q * 4 + reg;   // frame
    const float mu = f0_to_norm(f0[row], f0b[row >> 6]);
    const float sd = fminf(fmaxf(nstd[row], 1e-12f), 1.0f) * F0_DIFF;
    const float inv_sd = 1.0f / sd;
    const float a = inv_sd * (1.0f / 256.0f);
    const float bmu = mu * inv_sd;
#pragma unroll
    for (int ni = 0; ni < 4; ++ni) {
      const int col = bn0 + ni * 16 + r;             // kappa
      const int k = col & 127;
      float z = fmaf((float)k, a, -bmu);
      float cf = (k == 0) ? (1.0f / 512.0f) : (2.0f / 512.0f);
      float s = cf * exp2f(z * z * -0.72134752044f);  // exp(-z^2/2)
      Cout[(size_t)row * 256 + col] = (_Float16)(acc[ni][reg] * s);
    }
  }
}

// ---------------------------------------------------------------------------
// Kernel 3: fused inverse DFT + overlap-add + oscillator bank + mix.
// Linear 512-block grid with the same XCD-chunked swizzle: the 4 n0-blocks
// of one (b,e) co-locate on an XCD (AB re-reads become L2 hits).
// Phase from the closed form of cumsum(lin_interp(f0n)).
// ---------------------------------------------------------------------------
__global__ __launch_bounds__(256) void invfin_k(const _Float16* __restrict__ AB,
                                                const _Float16* __restrict__ W2,
                                                const float* __restrict__ f0,
                                                const float* __restrict__ f0b,
                                                const float* __restrict__ oenv_g,
                                                const float* __restrict__ oscenv_g,
                                                const float* __restrict__ henv_g,
                                                float* __restrict__ out) {
  const int p = blockIdx.x;                // [0,512)
  const int x = p & 7, j = p >> 3;
  const int be = ((j >> 2) << 3) + x;      // [0,128)
  const int n0 = (j & 3) * 64;             // sample-within-chunk base
  const int m0 = be * 64;                  // global chunk base
  const int tid = threadIdx.x;
  const int wave = tid >> 6, lane = tid & 63;
  const int r = lane & 15, q = lane >> 4;

  __shared__ __align__(16) _Float16 Ash[65 * 64];    // rows: AB[m0-1 .. m0+63]
  __shared__ __align__(16) _Float16 B1sh[64 * 64];   // W2[n0+row]
  __shared__ __align__(16) _Float16 B2sh[64 * 64];   // W2[n0+row+256]
  __shared__ __align__(16) float4 qe4[8 * SEQ];
  __shared__ float oenv[SEQ], oscE[SEQ];
  __shared__ float Fs[SEQ], Ds[SEQ], Gs[SEQ];

  if (tid < SEQ) {
    oenv[tid] = clip01(oenv_g[be * SEQ + tid]);
    oscE[tid] = clip01(oscenv_g[be * SEQ + tid]);
    Fs[tid] = f0_to_norm(f0[be * SEQ + tid], f0b[be]);
  }
  __syncthreads();

  // wave 0: segment phase-prefix scan (f64, 6 shuffle steps), mod 2
  if (tid < SEQ) {
    const int s = tid;
    float fcur = Fs[s];
    float fnxt = (s < 63) ? Fs[s + 1] : Fs[63];
    Ds[s] = fnxt - fcur;                               // D[63] = 0
    double term = 128.0 * ((double)fcur + (double)fnxt);
    double sc = term;
#pragma unroll
    for (int off = 1; off < 64; off <<= 1) {
      double u = __shfl_up(sc, off, 64);
      if (s >= off) sc += u;
    }
    double C = 128.0 * (double)Fs[0] + (sc - term);    // exclusive prefix
    Gs[s] = (float)(C - 2.0 * floor(C * 0.5));
  }

  // stage qe4 (osc_env * harm_env)
  for (int idx = tid; idx < 8 * SEQ; idx += 256) {
    int hq = idx >> 6, s = idx & 63;
    const float* hb = henv_g + (size_t)be * (NHARM * SEQ) + (4 * hq) * SEQ + s;
    float e = oscE[s];
    qe4[idx] = make_float4(e * clip01(hb[0]), e * clip01(hb[64]),
                           e * clip01(hb[128]), e * clip01(hb[192]));
  }

  auto stage_AB = [&](int kk) {
#pragma unroll
    for (int it = 0; it < 3; ++it) {
      int g = it * 256 + tid;
      if (g < 520) {
        int row = g >> 3, kg = g & 7;
        half8 v = {0, 0, 0, 0, 0, 0, 0, 0};
        if (row > 0)
          v = *(const half8*)(AB + (size_t)(m0 - 1 + row) * 256 + kk + kg * 8);
        *(half8*)(&Ash[row * 64 + ((kg ^ (row & 7)) << 3)]) = v;
      }
    }
#pragma unroll
    for (int it = 0; it < 4; ++it) {
      int g = it * 256 + tid;
      int row = (g >> 3) & 63, kg = g & 7;
      bool second = g >= 512;
      int wrow = n0 + row + (second ? 256 : 0);
      half8 v = *(const half8*)(W2 + (size_t)wrow * 256 + kk + kg * 8);
      _Float16* dst = second ? B2sh : B1sh;
      *(half8*)(&dst[row * 64 + ((kg ^ (row & 7)) << 3)]) = v;
    }
  };

  f32x4 acc[4] = {};
  stage_AB(0);
  __syncthreads();

  for (int t = 0;;) {
#pragma unroll
    for (int ks = 0; ks < 2; ++ks) {
      const int kg = ks * 4 + q;
      const int ra1 = 1 + wave * 16 + r;
      const int ra2 = wave * 16 + r;
      half8 af1 = *(const half8*)(&Ash[ra1 * 64 + ((kg ^ (ra1 & 7)) << 3)]);
      half8 af2 = *(const half8*)(&Ash[ra2 * 64 + ((kg ^ (ra2 & 7)) << 3)]);
#pragma unroll
      for (int ni = 0; ni < 4; ++ni) {
        const int rb = ni * 16 + r;
        const int sw = (kg ^ (rb & 7)) << 3;
        half8 bf1 = *(const half8*)(&B1sh[rb * 64 + sw]);
        half8 bf2 = *(const half8*)(&B2sh[rb * 64 + sw]);
        acc[ni] = __builtin_amdgcn_mfma_f32_16x16x32_f16(af1, bf1, acc[ni], 0, 0, 0);
        acc[ni] = __builtin_amdgcn_mfma_f32_16x16x32_f16(af2, bf2, acc[ni], 0, 0, 0);
      }
    }
    if (t == 3) break;
    __syncthreads();
    stage_AB((t + 1) << 6);
    __syncthreads();
    ++t;
  }

  // epilogue: analytic phase + oscillator bank + mix, in-register
#pragma unroll
  for (int reg = 0; reg < 4; ++reg) {
    const int c = wave * 16 + q * 4 + reg;           // chunk within be
#pragma unroll
    for (int ni = 0; ni < 4; ++ni) {
      const int n = n0 + ni * 16 + r;
      const int t = c * 256 + n;
      float pos = ((float)t + 0.5f) * (1.0f / 256.0f) - 0.5f;
      pos = fminf(fmaxf(pos, 0.0f), 63.0f);
      int i0 = (int)pos;
      int i1 = min(i0 + 1, 63);
      float w = pos - (float)i0;

      float pph;
      if (t < 128) {
        pph = (float)(t + 1) * Fs[0];
      } else {
        int s = (t - 128) >> 8;
        float u1 = (float)((t - 128) - (s << 8) + 1);
        pph = Gs[s] + fmaf(Ds[s] * (1.0f / 512.0f), u1 * u1, u1 * Fs[s]);
      }
      pph = pph - 2.0f * floorf(pph * 0.5f);         // phase mod 2 (pi units)
      float xv = pph * 0.5f;
      float sb = sin_rev(xv);
      float cb = cos_rev(xv);
      float C = 2.0f * cb;

      float fund = sb * (oscE[i0] * (1.0f - w) + oscE[i1] * w);
      float d0 = 0.0f, d1 = 0.0f;
      float sp = sb;
      float scur = C * sb;
#pragma unroll
      for (int hq = 0; hq < 8; ++hq) {
        float4 qa = qe4[hq * 64 + i0];
        float4 qb = qe4[hq * 64 + i1];
        d0 = fmaf(scur, qa.x, d0); d1 = fmaf(scur, qb.x, d1);
        sp = fmaf(C, scur, -sp);
        d0 = fmaf(sp, qa.y, d0);   d1 = fmaf(sp, qb.y, d1);
        scur = fmaf(C, sp, -scur);
        d0 = fmaf(scur, qa.z, d0); d1 = fmaf(scur, qb.z, d1);
        sp = fmaf(C, scur, -sp);
        d0 = fmaf(sp, qa.w, d0);   d1 = fmaf(sp, qb.w, d1);
        scur = fmaf(C, sp, -scur);
      }
      float osc = fund + d0 * (1.0f - w) + d1 * w;
      float mix = oenv[i0] * (1.0f - w) + oenv[i1] * w;
      out[(size_t)be * NSAMP + t] = fmaf(osc, mix, acc[ni][reg] * (1.0f - mix));
    }
  }
}

// ---------------------------------------------------------------------------
extern "C" void kernel_launch(void* const* d_in, const int* in_sizes, int n_in,
                              void* d_out, int out_size, void* d_ws, size_t ws_size,
                              hipStream_t stream) {
  const float* f0           = (const float*)d_in[0];
  const float* overall_env  = (const float*)d_in[1];
  const float* osc_env      = (const float*)d_in[2];
  // d_in[3] = noise_env: unused by the reference
  const float* harm_env     = (const float*)d_in[4];
  const float* noise_std    = (const float*)d_in[5];
  const float* f0_base      = (const float*)d_in[6];
  const float* noise_frames = (const float*)d_in[7];
  float* out = (float*)d_out;

  // workspace layout
  _Float16* W1 = (_Float16*)d_ws;                         // 131,072 f16
  _Float16* W2 = W1 + 256 * 512;                          // 131,072 f16
  _Float16* AB = W2 + 512 * 256;                          // 2,097,152 f16

  prep_k<<<256, 256, 0, stream>>>(W1);
  // fwd: AB = filt( hann(frames) x W1^T ) ; also generates W2 (blocks 0..255)
  gemmf_k<<<768, 256, 0, stream>>>(noise_frames, W1, AB, W2, f0, noise_std, f0_base);
  // inv + OLA + oscillator bank + final mix, writes out directly
  invfin_k<<<512, 256, 0, stream>>>(
      AB, W2, f0, f0_base, overall_env, osc_env, harm_env, out);
}